// Round 13
// baseline (508.460 us; speedup 1.0000x reference)
//
#include <hip/hip_runtime.h>

#define VMC(n) asm volatile("s_waitcnt vmcnt(" #n ")" ::: "memory")
#define LGKM0() asm volatile("s_waitcnt lgkmcnt(0)" ::: "memory")

namespace {

constexpr int Bc = 4;
constexpr int Cc = 256;
constexpr int Pc = 128;
constexpr int NcT = 3136;  // true spatial size 56*56
constexpr int Np = 3200;   // padded to 25*128
constexpr int Sc = 5;
constexpr int KSn = 5;     // split-K chunks for abt (3200 = 5*640)
constexpr int KCH = 640;
constexpr float EPSc = 1e-5f;

typedef __attribute__((ext_vector_type(8))) short bf16x8;
typedef __attribute__((ext_vector_type(4))) float f32x4;
typedef __attribute__((ext_vector_type(8))) unsigned short u16x8;
typedef __attribute__((ext_vector_type(4))) unsigned short u16x4;

__device__ inline float bf2f(unsigned short u) {
    return __uint_as_float(((unsigned)u) << 16);
}
__device__ inline unsigned short f2bf(float f) {
    unsigned u = __float_as_uint(f);
    return (unsigned short)((u + 0x7FFFu + ((u >> 16) & 1u)) >> 16);
}

struct GP {
    const unsigned short* A; int lda; long aB; long aSl;
    const unsigned short* Bw; int ldb; long bB; long bSl;
    const unsigned short* A2; int lda2; long aB2;
    const unsigned short* B2; int ldb2; long bB2;
    int K; int K2; int nsl; int kchunk;
    unsigned short* outSM; int ldsm; long smB; long smSlice;
    unsigned short* outCM; long cmB;
    float* ps; float* ps2;
    const float* bnsc; const float* bnsh;   // FUSEBN precomputed scale/shift
    const float* dinv;
    const unsigned short* oin;
    float* resid;
};

// manual subset barrier: agent-scope counter (non-coherent XCD safe)
__device__ inline void signal_flag(unsigned* f) {
    __syncthreads();
    if (threadIdx.x == 0)
        __hip_atomic_fetch_add(f, 1u, __ATOMIC_RELEASE, __HIP_MEMORY_SCOPE_AGENT);
}
__device__ inline void wait_flag(unsigned* f, unsigned target) {
    if (threadIdx.x == 0) {
        int guard = 0;
        while (__hip_atomic_load(f, __ATOMIC_ACQUIRE,
                                 __HIP_MEMORY_SCOPE_AGENT) < target) {
            __builtin_amdgcn_s_sleep(8);
            if (++guard > (1 << 20)) break;   // bounded: fail fast, don't wedge
        }
    }
    __syncthreads();
}

// ---------------------------------------------------------------------------
// MFMA GEMM body (round-12 pipelined version, blockIdx -> args).
// Tile MT(m) x 128(n), 4 waves, K-step 64. Non-FUSEBN: 4-buffer depth-3
// pipeline, counted vmcnt + raw s_barrier. FUSEBN: explicit 4-step depth-2
// register-prefetch pipeline. Staging via global_load_lds(16B), granule
// swizzle phys = g ^ (row&7).
// ---------------------------------------------------------------------------
template <int MT, int EPI, int CMOUT, bool SPLITK, int BNSTAT, bool FUSEBN,
          bool XORM, bool DUALK>
__device__ void gemm_body(char* lds, int bx, int by, int bz, int MY, const GP& p)
{
    constexpr int TBA = MT * 64 * 2;
    constexpr int TBB = 128 * 64 * 2;
    constexpr int BUF = TBA + TBB;
    constexpr int OTB = MT * 132 * 4;

    int b, kstart;
    long smOff;
    if (SPLITK) {
        b = bz & 3;
        int ks = bz >> 2;
        kstart = ks * p.kchunk;
        smOff = (long)ks * p.smSlice;
    } else {
        b = bz; kstart = 0; smOff = 0;
    }
    const int n0 = bx * 128;
    const int m0 = by * MT;
    const int tid = threadIdx.x;
    const int w = tid >> 6, l = tid & 63;

    const unsigned short* Ab = p.A + (size_t)b * p.aB + (size_t)m0 * p.lda;
    const unsigned short* Bb = p.Bw + (size_t)b * p.bB + (size_t)n0 * p.ldb;

    const int srow8 = tid >> 3;
    const int sgran = tid & 7;
    const int sswz = (sgran ^ (srow8 & 7)) * 8;
    constexpr int AR = MT / 32;

    constexpr int WC = (MT == 128) ? 2 : 4;
    constexpr int NB = 128 / WC / 16;
    const int wr = w / WC, wc = w % WC;

    f32x4 acc[4][NB] = {};

    float4 dvv[4];
    if constexpr (DUALK) {
#pragma unroll
        for (int r = 0; r < 4; ++r) {
            float4 v = *(const float4*)(p.dinv + (size_t)b * Np + m0 +
                                        wr * 64 + r * 16 + (l >> 4) * 4);
            v.x *= 0.5f; v.y *= 0.5f; v.z *= 0.5f; v.w *= 0.5f;
            dvv[r] = v;
        }
    }

    auto stage1 = [&](int buf, int sl, int k0) {
        char* base = lds + buf * BUF;
        const unsigned short* As = Ab + (size_t)sl * p.aSl + k0 + sswz;
#pragma unroll
        for (int j = 0; j < AR; ++j)
            __builtin_amdgcn_global_load_lds(
                (const __attribute__((address_space(1))) void*)
                    (As + (size_t)(j * 32 + srow8) * p.lda),
                (__attribute__((address_space(3))) void*)(base + j * 4096 + tid * 16),
                16, 0, 0);
        const unsigned short* Bs = Bb + (size_t)sl * p.bSl + k0 + sswz;
#pragma unroll
        for (int j = 0; j < 4; ++j)
            __builtin_amdgcn_global_load_lds(
                (const __attribute__((address_space(1))) void*)
                    (Bs + (size_t)(j * 32 + srow8) * p.ldb),
                (__attribute__((address_space(3))) void*)(base + TBA + j * 4096 + tid * 16),
                16, 0, 0);
    };

    auto stageB1 = [&](int buf, int k0) {
        char* base = lds + buf * BUF + TBA;
        const unsigned short* Bs = Bb + k0 + sswz;
#pragma unroll
        for (int j = 0; j < 4; ++j)
            __builtin_amdgcn_global_load_lds(
                (const __attribute__((address_space(1))) void*)
                    (Bs + (size_t)(j * 32 + srow8) * p.ldb),
                (__attribute__((address_space(3))) void*)(base + j * 4096 + tid * 16),
                16, 0, 0);
    };

    auto compute = [&](int buf) {
        const char* base = lds + buf * BUF;
        const int lo = l & 15, gq = l >> 4;
#pragma unroll
        for (int kh = 0; kh < 2; ++kh) {
            const int lg = kh * 4 + gq;
            bf16x8 bf[NB];
#pragma unroll
            for (int c = 0; c < NB; ++c) {
                int brow = wc * (16 * NB) + c * 16 + lo;
                bf[c] = *(const bf16x8*)(base + TBA + brow * 128 +
                                         ((lg ^ (brow & 7)) << 4));
            }
#pragma unroll
            for (int r = 0; r < 4; ++r) {
                int arow = wr * 64 + r * 16 + lo;
                bf16x8 af = *(const bf16x8*)(base + arow * 128 +
                                             ((lg ^ (arow & 7)) << 4));
#pragma unroll
                for (int c = 0; c < NB; ++c)
                    acc[r][c] = __builtin_amdgcn_mfma_f32_16x16x32_bf16(
                        af, bf[c], acc[r][c], 0, 0, 0);
            }
        }
    };

    if constexpr (FUSEBN) {
        struct FB {
            u16x8 ov[AR]; float4 r0[AR], r1[AR];
            float4 s0, s1, h0, h1; int k0;
        };
        FB fA, fB;
        auto fbIssue = [&](FB& f, int k0) {   // 10 vm loads
            f.k0 = k0;
            f.s0 = *(const float4*)(p.bnsc + k0 + sgran * 8);
            f.s1 = *(const float4*)(p.bnsc + k0 + sgran * 8 + 4);
            f.h0 = *(const float4*)(p.bnsh + k0 + sgran * 8);
            f.h1 = *(const float4*)(p.bnsh + k0 + sgran * 8 + 4);
#pragma unroll
            for (int j = 0; j < AR; ++j) {
                size_t off = ((size_t)b * Np + (m0 + j * 32 + srow8)) * 256 +
                             k0 + sgran * 8;
                f.ov[j] = *(const u16x8*)(p.oin + off);
                f.r0[j] = *(const float4*)(p.resid + off);
                f.r1[j] = *(const float4*)(p.resid + off + 4);
            }
        };
        auto fbFin = [&](FB& f, int buf) {
            char* base = lds + buf * BUF;
#pragma unroll
            for (int j = 0; j < AR; ++j) {
                int row = j * 32 + srow8;
                int n = m0 + row;
                size_t off = ((size_t)b * Np + n) * 256 + f.k0 + sgran * 8;
                bool real = (n < NcT);
                float fu[8];
                fu[0] = real ? f.r0[j].x + fmaf(bf2f(f.ov[j][0]), f.s0.x, f.h0.x) : 0.f;
                fu[1] = real ? f.r0[j].y + fmaf(bf2f(f.ov[j][1]), f.s0.y, f.h0.y) : 0.f;
                fu[2] = real ? f.r0[j].z + fmaf(bf2f(f.ov[j][2]), f.s0.z, f.h0.z) : 0.f;
                fu[3] = real ? f.r0[j].w + fmaf(bf2f(f.ov[j][3]), f.s0.w, f.h0.w) : 0.f;
                fu[4] = real ? f.r1[j].x + fmaf(bf2f(f.ov[j][4]), f.s1.x, f.h1.x) : 0.f;
                fu[5] = real ? f.r1[j].y + fmaf(bf2f(f.ov[j][5]), f.s1.y, f.h1.y) : 0.f;
                fu[6] = real ? f.r1[j].z + fmaf(bf2f(f.ov[j][6]), f.s1.z, f.h1.z) : 0.f;
                fu[7] = real ? f.r1[j].w + fmaf(bf2f(f.ov[j][7]), f.s1.w, f.h1.w) : 0.f;
                float4 w0, w1;
                w0.x = fu[0]; w0.y = fu[1]; w0.z = fu[2]; w0.w = fu[3];
                w1.x = fu[4]; w1.y = fu[5]; w1.z = fu[6]; w1.w = fu[7];
                *(float4*)(p.resid + off) = w0;
                *(float4*)(p.resid + off + 4) = w1;
                u16x8 hv;
#pragma unroll
                for (int i = 0; i < 8; ++i) hv[i] = f2bf(fu[i]);
                *(u16x8*)(base + row * 128 + ((sgran ^ (row & 7)) << 4)) = hv;
            }
        };

        fbIssue(fA, kstart);        stageB1(0, kstart);
        fbIssue(fB, kstart + 64);   stageB1(1, kstart + 64);
        VMC(14);
        fbFin(fA, 0);
        fbIssue(fA, kstart + 128);  stageB1(2, kstart + 128);
        LGKM0();
        __builtin_amdgcn_s_barrier();
        __builtin_amdgcn_sched_barrier(0);
        compute(0);
        VMC(18);
        fbFin(fB, 1);
        fbIssue(fB, kstart + 192);  stageB1(3, kstart + 192);
        LGKM0();
        __builtin_amdgcn_s_barrier();
        __builtin_amdgcn_sched_barrier(0);
        compute(1);
        VMC(18);
        fbFin(fA, 2);
        LGKM0();
        __builtin_amdgcn_s_barrier();
        __builtin_amdgcn_sched_barrier(0);
        compute(2);
        VMC(4);
        fbFin(fB, 3);
        LGKM0();
        __builtin_amdgcn_s_barrier();
        __builtin_amdgcn_sched_barrier(0);
        compute(3);
        __syncthreads();
    } else {
        const int nsteps1 = (SPLITK ? p.kchunk : p.K) >> 6;
        const int spl2 = DUALK ? (p.K2 >> 6) : 0;
        const int loop1 = p.nsl * nsteps1;
        const int tot = loop1 + spl2;

        const unsigned short* Ab2 = DUALK ?
            (p.A2 + (size_t)b * p.aB2 + (size_t)m0 * p.lda2) : nullptr;
        const unsigned short* Bb2 = DUALK ?
            (p.B2 + (size_t)b * p.bB2 + (size_t)n0 * p.ldb2) : nullptr;
        auto stage2 = [&](int buf, int k0) {
            if constexpr (DUALK) {
                char* base = lds + buf * BUF;
                const unsigned short* As = Ab2 + k0 + sswz;
#pragma unroll
                for (int j = 0; j < AR; ++j)
                    __builtin_amdgcn_global_load_lds(
                        (const __attribute__((address_space(1))) void*)
                            (As + (size_t)(j * 32 + srow8) * p.lda2),
                        (__attribute__((address_space(3))) void*)(base + j * 4096 + tid * 16),
                        16, 0, 0);
                const unsigned short* Bs = Bb2 + k0 + sswz;
#pragma unroll
                for (int j = 0; j < 4; ++j)
                    __builtin_amdgcn_global_load_lds(
                        (const __attribute__((address_space(1))) void*)
                            (Bs + (size_t)(j * 32 + srow8) * p.ldb2),
                        (__attribute__((address_space(3))) void*)(base + TBA + j * 4096 + tid * 16),
                        16, 0, 0);
            }
        };

        auto stage_g = [&](int buf, int g) {
            if (g < loop1) {
                int sl = g / nsteps1;
                int st = g - sl * nsteps1;
                stage1(buf, sl, kstart + (st << 6));
            } else {
                stage2(buf, (g - loop1) << 6);
            }
        };

        stage_g(0, 0);
        if (1 < tot) stage_g(1, 1);
        if (2 < tot) stage_g(2, 2);
        for (int gs = 0; gs < tot; ++gs) {
            if constexpr (MT == 64) {
                if (gs + 2 < tot) VMC(12);
                else if (gs + 1 < tot) VMC(6);
                else VMC(0);
            } else {
                if (gs + 2 < tot) VMC(16);
                else if (gs + 1 < tot) VMC(8);
                else VMC(0);
            }
            __builtin_amdgcn_s_barrier();
            __builtin_amdgcn_sched_barrier(0);
            if (gs + 3 < tot) stage_g((gs + 3) & 3, gs + 3);
            compute(gs & 3);
            if constexpr (DUALK) {
                if (gs == loop1 - 1) {
#pragma unroll
                    for (int r = 0; r < 4; ++r) {
#pragma unroll
                        for (int c = 0; c < NB; ++c) {
                            acc[r][c][0] *= dvv[r].x;
                            acc[r][c][1] *= dvv[r].y;
                            acc[r][c][2] *= dvv[r].z;
                            acc[r][c][3] *= dvv[r].w;
                        }
                    }
                }
            }
        }
        __syncthreads();
    }

    // stage accumulators to LDS f32 [MT][132]
    float* ot = (float*)lds;
    {
        const int lo = l & 15, gq = l >> 4;
#pragma unroll
        for (int r = 0; r < 4; ++r)
#pragma unroll
            for (int c = 0; c < NB; ++c)
#pragma unroll
                for (int j = 0; j < 4; ++j) {
                    float v = acc[r][c][j];
                    if (EPI == 1) v = fmaxf(v, 0.f);
                    ot[(wr * 64 + r * 16 + gq * 4 + j) * 132 +
                       wc * (16 * NB) + c * 16 + lo] = v;
                }
    }
    __syncthreads();

    {   // row-major store
        constexpr int TPR = 256 / MT;
        const int r = tid / TPR;
        const int c0 = (tid % TPR) * (MT / 2);
        const int m0s = XORM ? (m0 ^ 128) : m0;
        unsigned short* dst = p.outSM + (size_t)b * p.smB + smOff +
                              (size_t)(m0s + r) * p.ldsm + n0 + c0;
#pragma unroll
        for (int k = 0; k < MT / 16; ++k) {
            u16x8 o;
#pragma unroll
            for (int j = 0; j < 8; ++j) o[j] = f2bf(ot[r * 132 + c0 + 8 * k + j]);
            *(u16x8*)(dst + 8 * k) = o;
        }
    }

    if (CMOUT) {
        const int c = tid >> 1, r0 = (tid & 1) * (MT / 2);
        const float* dv = p.dinv + (size_t)b * Np + m0 + r0;
        unsigned short* dst = p.outCM + (size_t)b * p.cmB +
                              (size_t)(n0 + c) * Np + m0 + r0;
#pragma unroll
        for (int k = 0; k < MT / 16; ++k) {
            u16x8 o;
#pragma unroll
            for (int j = 0; j < 8; ++j) {
                float v = ot[(r0 + 8 * k + j) * 132 + c];
                if (CMOUT == 2) v *= dv[8 * k + j];
                o[j] = f2bf(v);
            }
            *(u16x8*)(dst + 8 * k) = o;
        }
    }

    if (BNSTAT) {
        float* p1 = (float*)(lds + OTB);
        float* p2 = p1 + 256;
        const int col = tid & 127, half = tid >> 7;
        float s = 0.f, s2 = 0.f;
#pragma unroll
        for (int i = 0; i < MT / 2; ++i) {
            float v = ot[(half * (MT / 2) + i) * 132 + col];
            s += v;
            if (BNSTAT == 2) s2 = fmaf(v, v, s2);
        }
        p1[half * 128 + col] = s;
        if (BNSTAT == 2) p2[half * 128 + col] = s2;
        __syncthreads();
        if (tid < 128) {
            float aa = p1[tid] + p1[128 + tid];
            size_t slot = ((size_t)b * MY + by) * 256 + n0 + tid;
            p.ps[slot] = aa;
            if (BNSTAT == 2) p.ps2[slot] = p2[tid] + p2[128 + tid];
        }
    }
    __syncthreads();   // LDS safe for next phase
}

// BN finalize body: 16 blocks x 16 channels; 100 partial groups
__device__ void bnfin_body(char* ldsb, int bid,
                           const float* __restrict__ ps,
                           const float* __restrict__ ps2,
                           const float* __restrict__ gamma,
                           const float* __restrict__ beta,
                           float* __restrict__ scale, float* __restrict__ shift)
{
    float* l1 = (float*)ldsb;
    float* l2 = l1 + 256;
    int t = threadIdx.x;
    int c = bid * 16 + (t & 15);
    int gl = t >> 4;
    float a = 0.f, a2 = 0.f;
    for (int g = gl; g < 100; g += 16) {
        a += ps[(size_t)g * 256 + c];
        a2 += ps2[(size_t)g * 256 + c];
    }
    l1[t] = a; l2[t] = a2;
    __syncthreads();
    if (gl == 0) {
#pragma unroll
        for (int j = 1; j < 16; ++j) {
            a += l1[j * 16 + (t & 15)];
            a2 += l2[j * 16 + (t & 15)];
        }
        const float inv = 1.f / (float)(Bc * NcT);
        float mean = a * inv;
        float var = a2 * inv - mean * mean;
        float sc = gamma[c] * rsqrtf(var + EPSc);
        scale[c] = sc;
        shift[c] = beta[c] - mean * sc;
    }
}

// standalone mgemm wrapper (used for the U projection only)
template <int MT, int EPI, int CMOUT, bool SPLITK, int BNSTAT, bool FUSEBN,
          bool XORM, bool DUALK>
__global__ __launch_bounds__(256) void mgemm_g(GP p)
{
    constexpr int TBA = MT * 64 * 2;
    constexpr int BUF = TBA + 128 * 64 * 2;
    constexpr int OTB = MT * 132 * 4;
    constexpr int LDSZ = (4 * BUF > OTB + 2048) ? 4 * BUF : (OTB + 2048);
    __shared__ __align__(16) char lds[LDSZ];
    gemm_body<MT, EPI, CMOUT, SPLITK, BNSTAT, FUSEBN, XORM, DUALK>(
        lds, blockIdx.x, blockIdx.y, blockIdx.z, (int)gridDim.y, p);
}

// ---------------------------------------------------------------------------
// Fused per-stage kernel: 200 blocks, manual subset barriers.
//   P1 g(200) -> P2 abt(80) -> P3 WM(32) -> P4 o(200) -> P5 bnfin(16)
// ---------------------------------------------------------------------------
struct SP {
    GP g, abt, wm, o;
    const float* ps; const float* ps2;
    const float* gammap; const float* betap;
    float* scale; float* shiftb;
    unsigned* flags;   // 4 counters, zeroed per launch
};

template <bool FIRST>
__global__ __launch_bounds__(256) void stage_k(SP sp)
{
    __shared__ __align__(16) char lds[131072];
    const int bid = blockIdx.x;

    // P1: g = Wg[s] @ out (FUSEBN applies previous stage's BN to residual)
    gemm_body<64, 0, 2, false, 0, (FIRST ? false : true), false, false>(
        lds, 0, bid % 50, bid / 50, 50, sp.g);
    signal_flag(&sp.flags[0]);

    // P2: abt split-K partials
    if (bid < 80) {
        wait_flag(&sp.flags[0], 200);
        gemm_body<64, 0, 0, true, 0, false, true, false>(
            lds, 0, bid % 4, bid / 4, 4, sp.abt);
        signal_flag(&sp.flags[1]);
    }
    // P3: WM = W1 @ Mst (slice-accumulating Cpart)
    if (bid < 32) {
        wait_flag(&sp.flags[1], 80);
        gemm_body<64, 0, 0, false, 0, false, false, false>(
            lds, bid % 2, (bid / 2) % 4, bid / 8, 4, sp.wm);
        signal_flag(&sp.flags[2]);
    }
    // P4: o = (U @ WM^T)*0.5*dinv + g @ W2^T + BN partial stats
    wait_flag(&sp.flags[2], 32);
    gemm_body<128, 0, 0, false, 2, false, false, true>(
        lds, bid % 2, (bid / 2) % 25, bid / 50, 25, sp.o);
    signal_flag(&sp.flags[3]);

    // P5: BN finalize -> scale/shift for next stage
    if (bid < 16) {
        wait_flag(&sp.flags[3], 200);
        bnfin_body(lds, bid, sp.ps, sp.ps2, sp.gammap, sp.betap,
                   sp.scale, sp.shiftb);
    }
}

// ---------------------------------------------------------------------------
// prep: weight f32->bf16 (544 items) + input transpose (800 items)
// ---------------------------------------------------------------------------
__global__ __launch_bounds__(256) void prep_k(
    const float* __restrict__ x, const float* __restrict__ Wt,
    const float* __restrict__ Wp, const float* __restrict__ Wg,
    const float* __restrict__ W1, const float* __restrict__ W2,
    unsigned short* __restrict__ Wcomb, unsigned short* __restrict__ Wgh,
    unsigned short* __restrict__ W1h, unsigned short* __restrict__ W2h,
    float* __restrict__ out_sm, unsigned short* __restrict__ outh)
{
    __shared__ float tb[64][65];
    int item = blockIdx.x;
    int t = threadIdx.x;
    if (item < 544) {
        size_t e = ((size_t)item * 256 + t) * 4;
        const float* src; unsigned short* dst;
        if (e < 32768)       { src = Wt + e;           dst = Wcomb + e; }
        else if (e < 65536)  { src = Wp + (e - 32768); dst = Wcomb + e; }
        else if (e < 229376) { size_t o = e - 65536;  src = Wg + o; dst = Wgh + o; }
        else if (e < 393216) { size_t o = e - 229376; src = W1 + o; dst = W1h + o; }
        else                 { size_t o = e - 393216; src = W2 + o; dst = W2h + o; }
        float4 v = *(const float4*)src;
        u16x4 t4;
        t4[0] = f2bf(v.x); t4[1] = f2bf(v.y); t4[2] = f2bf(v.z); t4[3] = f2bf(v.w);
        *(u16x4*)dst = t4;
        return;
    }
    int it = item - 544;
    int nx = it % 50, cy = (it / 50) % 4, b = it / 200;
    int c0 = cy * 64, n0 = nx * 64;
    const bool pad = (n0 >= NcT);
    if (!pad) {
        int ci = t >> 2, nb = (t & 3) * 16;
        const float* src = x + ((size_t)b * Cc + c0 + ci) * NcT + n0 + nb;
#pragma unroll
        for (int k = 0; k < 4; ++k) {
            float4 v = *(const float4*)(src + 4 * k);
            tb[ci][nb + 4 * k + 0] = v.x; tb[ci][nb + 4 * k + 1] = v.y;
            tb[ci][nb + 4 * k + 2] = v.z; tb[ci][nb + 4 * k + 3] = v.w;
        }
    }
    __syncthreads();
    int r = t >> 2, cb = (t & 3) * 16;
    size_t off = ((size_t)b * Np + n0 + r) * 256 + c0 + cb;
    float vv[16];
#pragma unroll
    for (int j = 0; j < 16; ++j) vv[j] = pad ? 0.f : tb[cb + j][r];
    float* dst = out_sm + off;
#pragma unroll
    for (int k = 0; k < 4; ++k) {
        float4 v; v.x = vv[4*k]; v.y = vv[4*k+1]; v.z = vv[4*k+2]; v.w = vv[4*k+3];
        *(float4*)(dst + 4 * k) = v;
    }
    u16x8 h1, h2;
#pragma unroll
    for (int j = 0; j < 8; ++j) { h1[j] = f2bf(vv[j]); h2[j] = f2bf(vv[8 + j]); }
    unsigned short* dh = outh + off;
    *(u16x8*)dh = h1;
    *(u16x8*)(dh + 8) = h2;
}

// dinv[b][i] = d>0 ? rsqrt(d) : 0, d = 0.5*sum_q U[b][i][q]*rs[b][q^128]
__global__ __launch_bounds__(256) void dinv_k(
    const unsigned short* __restrict__ U, const float* __restrict__ rp,
    float* __restrict__ dinv)
{
    __shared__ float rsl[256];
    int b = blockIdx.y, tid = threadIdx.x;
    float s = 0.f;
    for (int j = 0; j < 25; ++j) s += rp[((size_t)b * 25 + j) * 256 + tid];
    rsl[tid ^ 128] = s;
    __syncthreads();
    int i = blockIdx.x * 256 + tid;
    if (i < Np) {
        const unsigned short* row = U + ((size_t)b * Np + i) * 256;
        float acc = 0.f;
        for (int q0 = 0; q0 < 256; q0 += 8) {
            u16x8 v = *(const u16x8*)(row + q0);
#pragma unroll
            for (int j = 0; j < 8; ++j) acc = fmaf(bf2f(v[j]), rsl[q0 + j], acc);
        }
        float d = 0.5f * acc;
        dinv[(size_t)b * Np + i] = d > 0.f ? rsqrtf(d) : 0.f;
    }
}

// d_out[b][c][n] = transpose(out_sm + BN(o_sm))   (final stage fused)
__global__ __launch_bounds__(256) void xpoutbn_k(
    const float* __restrict__ out_sm, const unsigned short* __restrict__ oin,
    const float* __restrict__ scale, const float* __restrict__ shift,
    float* __restrict__ outp)
{
    __shared__ float tb[64][65];
    __shared__ float lsc[64], lsh[64];
    int b = blockIdx.z, c0 = blockIdx.y * 64, n0 = blockIdx.x * 64;
    int t = threadIdx.x;
    if (t < 64) { lsc[t] = scale[c0 + t]; lsh[t] = shift[c0 + t]; }
    __syncthreads();
    {
        int r = t >> 2, cb = (t & 3) * 16;
        size_t off = ((size_t)b * Np + n0 + r) * 256 + c0 + cb;
#pragma unroll
        for (int k = 0; k < 2; ++k) {
            float4 a0 = *(const float4*)(out_sm + off + 8 * k);
            float4 a1 = *(const float4*)(out_sm + off + 8 * k + 4);
            u16x8 ov = *(const u16x8*)(oin + off + 8 * k);
            tb[r][cb + 8*k + 0] = a0.x + fmaf(bf2f(ov[0]), lsc[cb + 8*k + 0], lsh[cb + 8*k + 0]);
            tb[r][cb + 8*k + 1] = a0.y + fmaf(bf2f(ov[1]), lsc[cb + 8*k + 1], lsh[cb + 8*k + 1]);
            tb[r][cb + 8*k + 2] = a0.z + fmaf(bf2f(ov[2]), lsc[cb + 8*k + 2], lsh[cb + 8*k + 2]);
            tb[r][cb + 8*k + 3] = a0.w + fmaf(bf2f(ov[3]), lsc[cb + 8*k + 3], lsh[cb + 8*k + 3]);
            tb[r][cb + 8*k + 4] = a1.x + fmaf(bf2f(ov[4]), lsc[cb + 8*k + 4], lsh[cb + 8*k + 4]);
            tb[r][cb + 8*k + 5] = a1.y + fmaf(bf2f(ov[5]), lsc[cb + 8*k + 5], lsh[cb + 8*k + 5]);
            tb[r][cb + 8*k + 6] = a1.z + fmaf(bf2f(ov[6]), lsc[cb + 8*k + 6], lsh[cb + 8*k + 6]);
            tb[r][cb + 8*k + 7] = a1.w + fmaf(bf2f(ov[7]), lsc[cb + 8*k + 7], lsh[cb + 8*k + 7]);
        }
    }
    __syncthreads();
    {
        int c = t >> 2, rb = (t & 3) * 16;
        float vv[16];
#pragma unroll
        for (int j = 0; j < 16; ++j) vv[j] = tb[rb + j][c];
        float* dst = outp + ((size_t)b * Cc + c0 + c) * NcT + n0 + rb;
#pragma unroll
        for (int k = 0; k < 4; ++k) {
            float4 v; v.x = vv[4*k]; v.y = vv[4*k+1]; v.z = vv[4*k+2]; v.w = vv[4*k+3];
            *(float4*)(dst + 4 * k) = v;
        }
    }
}

}  // namespace

extern "C" void kernel_launch(void* const* d_in, const int* in_sizes, int n_in,
                              void* d_out, int out_size, void* d_ws, size_t ws_size,
                              hipStream_t stream) {
    const float* x     = (const float*)d_in[0];
    const float* Wt    = (const float*)d_in[1];
    const float* Wp    = (const float*)d_in[2];
    const float* Wg    = (const float*)d_in[3];
    const float* W1    = (const float*)d_in[4];
    const float* W2    = (const float*)d_in[5];
    const float* gamma = (const float*)d_in[6];
    const float* beta  = (const float*)d_in[7];

    char* p = (char*)d_ws;
    auto alloc = [&](size_t bytes) { char* r = p; p += (bytes + 255) & ~(size_t)255; return r; };
    float*          out_sm = (float*)         alloc((size_t)Bc * Np * 256 * 4);
    unsigned short* outh   = (unsigned short*)alloc((size_t)Bc * Np * 256 * 2);
    unsigned short* U_sm   = (unsigned short*)alloc((size_t)Bc * Np * 256 * 2);
    unsigned short* U_cm   = (unsigned short*)alloc((size_t)Bc * 256 * Np * 2);
    unsigned short* g_sm   = (unsigned short*)alloc((size_t)Bc * Np * Pc * 2);
    unsigned short* g_cmd  = (unsigned short*)alloc((size_t)Bc * Pc * Np * 2);
    unsigned short* o_sm   = (unsigned short*)alloc((size_t)Bc * Np * 256 * 2);
    unsigned short* Cpart  = (unsigned short*)alloc((size_t)KSn * Bc * 256 * Pc * 2);
    unsigned short* WMb    = (unsigned short*)alloc((size_t)Bc * Cc * 256 * 2);
    unsigned short* Wcomb  = (unsigned short*)alloc((size_t)Cc * Cc * 2);
    unsigned short* Wgh    = (unsigned short*)alloc((size_t)Sc * Pc * Cc * 2);
    unsigned short* W1h    = (unsigned short*)alloc((size_t)Sc * Cc * Pc * 2);
    unsigned short* W2h    = (unsigned short*)alloc((size_t)Sc * Cc * Pc * 2);
    float*          rp     = (float*)         alloc((size_t)100 * 256 * 4);
    float*          dinv   = (float*)         alloc((size_t)Bc * Np * 4);
    float*          ps     = (float*)         alloc((size_t)100 * 256 * 4);
    float*          ps2    = (float*)         alloc((size_t)100 * 256 * 4);
    float*          scale  = (float*)         alloc(256 * 4);
    float*          shiftb = (float*)         alloc(256 * 4);
    unsigned*       flags  = (unsigned*)      alloc(Sc * 4 * sizeof(unsigned));

    const long NpC = (long)Np * 256;
    dim3 blk(256);

    hipMemsetAsync(flags, 0, Sc * 4 * sizeof(unsigned), stream);

    prep_k<<<1344, blk, 0, stream>>>(x, Wt, Wp, Wg, W1, W2,
                                     Wcomb, Wgh, W1h, W2h, out_sm, outh);

    // U = relu([Wt;Wp] @ x): spatial-major + col-major + col sums
    {
        GP g{};
        g.A = outh; g.lda = 256; g.aB = NpC; g.aSl = 0;
        g.Bw = Wcomb; g.ldb = 256; g.bB = 0; g.bSl = 0;
        g.K = 256; g.nsl = 1;
        g.outSM = U_sm; g.ldsm = 256; g.smB = NpC; g.smSlice = 0;
        g.outCM = U_cm; g.cmB = (long)256 * Np;
        g.ps = rp;
        mgemm_g<128, 1, 1, false, 1, false, false, false>
            <<<dim3(2, 25, Bc), blk, 0, stream>>>(g);
    }

    dinv_k<<<dim3(13, Bc), blk, 0, stream>>>(U_sm, rp, dinv);

    for (int s = 0; s < Sc; ++s) {
        SP sp{};
        // P1: g
        sp.g.A = outh; sp.g.lda = 256; sp.g.aB = NpC; sp.g.aSl = 0;
        sp.g.Bw = Wgh + (size_t)s * Pc * Cc; sp.g.ldb = 256; sp.g.bB = 0; sp.g.bSl = 0;
        sp.g.K = 256; sp.g.nsl = 1;
        sp.g.outSM = g_sm; sp.g.ldsm = 128; sp.g.smB = (long)Np * 128; sp.g.smSlice = 0;
        sp.g.outCM = g_cmd; sp.g.cmB = (long)Pc * Np;
        sp.g.dinv = dinv;
        sp.g.oin = o_sm; sp.g.bnsc = scale; sp.g.bnsh = shiftb; sp.g.resid = out_sm;
        // P2: abt
        sp.abt.A = U_cm; sp.abt.lda = Np; sp.abt.aB = (long)256 * Np; sp.abt.aSl = 0;
        sp.abt.Bw = g_cmd; sp.abt.ldb = Np; sp.abt.bB = (long)Pc * Np; sp.abt.bSl = 0;
        sp.abt.K = Np; sp.abt.kchunk = KCH; sp.abt.nsl = 1;
        sp.abt.outSM = Cpart; sp.abt.ldsm = 128; sp.abt.smB = (long)256 * Pc;
        sp.abt.smSlice = (long)Bc * 256 * Pc;
        // P3: WM
        sp.wm.A = W1h + (size_t)s * Cc * Pc; sp.wm.lda = 128; sp.wm.aB = 0; sp.wm.aSl = 0;
        sp.wm.Bw = Cpart; sp.wm.ldb = 128; sp.wm.bB = (long)256 * Pc;
        sp.wm.bSl = (long)Bc * 256 * Pc;
        sp.wm.K = 128; sp.wm.nsl = KSn;
        sp.wm.outSM = WMb; sp.wm.ldsm = 256; sp.wm.smB = (long)Cc * 256; sp.wm.smSlice = 0;
        // P4: o
        sp.o.A = U_sm; sp.o.lda = 256; sp.o.aB = NpC; sp.o.aSl = 0;
        sp.o.Bw = WMb; sp.o.ldb = 256; sp.o.bB = (long)Cc * 256; sp.o.bSl = 0;
        sp.o.K = 256; sp.o.nsl = 1;
        sp.o.A2 = g_sm; sp.o.lda2 = 128; sp.o.aB2 = (long)Np * 128;
        sp.o.B2 = W2h + (size_t)s * Cc * Pc; sp.o.ldb2 = 128; sp.o.bB2 = 0;
        sp.o.K2 = 128;
        sp.o.outSM = o_sm; sp.o.ldsm = 256; sp.o.smB = NpC; sp.o.smSlice = 0;
        sp.o.ps = ps; sp.o.ps2 = ps2;
        sp.o.dinv = dinv;
        // P5: bnfin
        sp.ps = ps; sp.ps2 = ps2;
        sp.gammap = gamma + (size_t)s * Cc;
        sp.betap = beta + (size_t)s * Cc;
        sp.scale = scale; sp.shiftb = shiftb;
        sp.flags = flags + s * 4;

        if (s == 0) stage_k<true><<<200, blk, 0, stream>>>(sp);
        else        stage_k<false><<<200, blk, 0, stream>>>(sp);
    }

    // final: d_out = transpose(out_sm + BN(o_sm))
    xpoutbn_k<<<dim3(49, 4, Bc), blk, 0, stream>>>(out_sm, o_sm, scale, shiftb,
                                                   (float*)d_out);
}

// Round 15
// 417.219 us; speedup vs baseline: 1.2187x; 1.2187x over previous
//
#include <hip/hip_runtime.h>

#define VMC(n) asm volatile("s_waitcnt vmcnt(" #n ")" ::: "memory")
#define LGKM0() asm volatile("s_waitcnt lgkmcnt(0)" ::: "memory")

namespace {

constexpr int Bc = 4;
constexpr int Cc = 256;
constexpr int Pc = 128;
constexpr int NcT = 3136;  // true spatial size 56*56
constexpr int Np = 3200;   // padded to 25*128
constexpr int Sc = 5;
constexpr int KSn = 5;     // split-K chunks for abt (3200 = 5*640)
constexpr int KCH = 640;
constexpr float EPSc = 1e-5f;

typedef __attribute__((ext_vector_type(8))) short bf16x8;
typedef __attribute__((ext_vector_type(4))) float f32x4;
typedef __attribute__((ext_vector_type(8))) unsigned short u16x8;
typedef __attribute__((ext_vector_type(4))) unsigned short u16x4;

__device__ inline float bf2f(unsigned short u) {
    return __uint_as_float(((unsigned)u) << 16);
}
__device__ inline unsigned short f2bf(float f) {
    unsigned u = __float_as_uint(f);
    return (unsigned short)((u + 0x7FFFu + ((u >> 16) & 1u)) >> 16);
}

struct GP {
    const unsigned short* A; int lda; long aB; long aSl;
    const unsigned short* Bw; int ldb; long bB; long bSl;
    const unsigned short* A2; int lda2; long aB2;
    const unsigned short* B2; int ldb2; long bB2;
    int K; int K2; int nsl; int kchunk;
    unsigned short* outSM; int ldsm; long smB; long smSlice;
    unsigned short* outCM; long cmB;
    float* ps; float* ps2;
    const float* bnsc; const float* bnsh;   // FUSEBN precomputed scale/shift
    const float* dinv;
    const unsigned short* oin;
    float* resid;
};

// manual subset barrier. Producer: one RELEASE add (L2 writeback, once per
// block). Consumer: RELAXED polling (no cache-invalidate per poll), then ONE
// ACQUIRE load for data visibility. Round-13's ACQUIRE-per-poll invalidated
// all XCD L2s continuously (33MB HBM refetch/stage, MfmaUtil 1.7%).
__device__ inline void signal_flag(unsigned* f) {
    __syncthreads();
    if (threadIdx.x == 0)
        __hip_atomic_fetch_add(f, 1u, __ATOMIC_RELEASE, __HIP_MEMORY_SCOPE_AGENT);
}
__device__ inline void wait_flag(unsigned* f, unsigned target) {
    if (threadIdx.x == 0) {
        int guard = 0;
        while (__hip_atomic_load(f, __ATOMIC_RELAXED,
                                 __HIP_MEMORY_SCOPE_AGENT) < target) {
            __builtin_amdgcn_s_sleep(2);
            if (++guard > (1 << 22)) break;   // bounded: fail fast, don't wedge
        }
        // single acquire for data visibility (one invalidate per barrier)
        (void)__hip_atomic_load(f, __ATOMIC_ACQUIRE, __HIP_MEMORY_SCOPE_AGENT);
    }
    __syncthreads();
}

// ---------------------------------------------------------------------------
// MFMA GEMM body (round-12 pipelined version, blockIdx -> args).
// Tile MT(m) x 128(n), 4 waves, K-step 64. Non-FUSEBN: 4-buffer depth-3
// pipeline, counted vmcnt + raw s_barrier. FUSEBN: explicit 4-step depth-2
// register-prefetch pipeline. Staging via global_load_lds(16B), granule
// swizzle phys = g ^ (row&7).
// ---------------------------------------------------------------------------
template <int MT, int EPI, int CMOUT, bool SPLITK, int BNSTAT, bool FUSEBN,
          bool XORM, bool DUALK>
__device__ void gemm_body(char* lds, int bx, int by, int bz, int MY, const GP& p)
{
    constexpr int TBA = MT * 64 * 2;
    constexpr int TBB = 128 * 64 * 2;
    constexpr int BUF = TBA + TBB;
    constexpr int OTB = MT * 132 * 4;

    int b, kstart;
    long smOff;
    if (SPLITK) {
        b = bz & 3;
        int ks = bz >> 2;
        kstart = ks * p.kchunk;
        smOff = (long)ks * p.smSlice;
    } else {
        b = bz; kstart = 0; smOff = 0;
    }
    const int n0 = bx * 128;
    const int m0 = by * MT;
    const int tid = threadIdx.x;
    const int w = tid >> 6, l = tid & 63;

    const unsigned short* Ab = p.A + (size_t)b * p.aB + (size_t)m0 * p.lda;
    const unsigned short* Bb = p.Bw + (size_t)b * p.bB + (size_t)n0 * p.ldb;

    const int srow8 = tid >> 3;
    const int sgran = tid & 7;
    const int sswz = (sgran ^ (srow8 & 7)) * 8;
    constexpr int AR = MT / 32;

    constexpr int WC = (MT == 128) ? 2 : 4;
    constexpr int NB = 128 / WC / 16;
    const int wr = w / WC, wc = w % WC;

    f32x4 acc[4][NB] = {};

    float4 dvv[4];
    if constexpr (DUALK) {
#pragma unroll
        for (int r = 0; r < 4; ++r) {
            float4 v = *(const float4*)(p.dinv + (size_t)b * Np + m0 +
                                        wr * 64 + r * 16 + (l >> 4) * 4);
            v.x *= 0.5f; v.y *= 0.5f; v.z *= 0.5f; v.w *= 0.5f;
            dvv[r] = v;
        }
    }

    auto stage1 = [&](int buf, int sl, int k0) {
        char* base = lds + buf * BUF;
        const unsigned short* As = Ab + (size_t)sl * p.aSl + k0 + sswz;
#pragma unroll
        for (int j = 0; j < AR; ++j)
            __builtin_amdgcn_global_load_lds(
                (const __attribute__((address_space(1))) void*)
                    (As + (size_t)(j * 32 + srow8) * p.lda),
                (__attribute__((address_space(3))) void*)(base + j * 4096 + tid * 16),
                16, 0, 0);
        const unsigned short* Bs = Bb + (size_t)sl * p.bSl + k0 + sswz;
#pragma unroll
        for (int j = 0; j < 4; ++j)
            __builtin_amdgcn_global_load_lds(
                (const __attribute__((address_space(1))) void*)
                    (Bs + (size_t)(j * 32 + srow8) * p.ldb),
                (__attribute__((address_space(3))) void*)(base + TBA + j * 4096 + tid * 16),
                16, 0, 0);
    };

    auto stageB1 = [&](int buf, int k0) {
        char* base = lds + buf * BUF + TBA;
        const unsigned short* Bs = Bb + k0 + sswz;
#pragma unroll
        for (int j = 0; j < 4; ++j)
            __builtin_amdgcn_global_load_lds(
                (const __attribute__((address_space(1))) void*)
                    (Bs + (size_t)(j * 32 + srow8) * p.ldb),
                (__attribute__((address_space(3))) void*)(base + j * 4096 + tid * 16),
                16, 0, 0);
    };

    auto compute = [&](int buf) {
        const char* base = lds + buf * BUF;
        const int lo = l & 15, gq = l >> 4;
#pragma unroll
        for (int kh = 0; kh < 2; ++kh) {
            const int lg = kh * 4 + gq;
            bf16x8 bf[NB];
#pragma unroll
            for (int c = 0; c < NB; ++c) {
                int brow = wc * (16 * NB) + c * 16 + lo;
                bf[c] = *(const bf16x8*)(base + TBA + brow * 128 +
                                         ((lg ^ (brow & 7)) << 4));
            }
#pragma unroll
            for (int r = 0; r < 4; ++r) {
                int arow = wr * 64 + r * 16 + lo;
                bf16x8 af = *(const bf16x8*)(base + arow * 128 +
                                             ((lg ^ (arow & 7)) << 4));
#pragma unroll
                for (int c = 0; c < NB; ++c)
                    acc[r][c] = __builtin_amdgcn_mfma_f32_16x16x32_bf16(
                        af, bf[c], acc[r][c], 0, 0, 0);
            }
        }
    };

    if constexpr (FUSEBN) {
        struct FB {
            u16x8 ov[AR]; float4 r0[AR], r1[AR];
            float4 s0, s1, h0, h1; int k0;
        };
        FB fA, fB;
        auto fbIssue = [&](FB& f, int k0) {   // 10 vm loads
            f.k0 = k0;
            f.s0 = *(const float4*)(p.bnsc + k0 + sgran * 8);
            f.s1 = *(const float4*)(p.bnsc + k0 + sgran * 8 + 4);
            f.h0 = *(const float4*)(p.bnsh + k0 + sgran * 8);
            f.h1 = *(const float4*)(p.bnsh + k0 + sgran * 8 + 4);
#pragma unroll
            for (int j = 0; j < AR; ++j) {
                size_t off = ((size_t)b * Np + (m0 + j * 32 + srow8)) * 256 +
                             k0 + sgran * 8;
                f.ov[j] = *(const u16x8*)(p.oin + off);
                f.r0[j] = *(const float4*)(p.resid + off);
                f.r1[j] = *(const float4*)(p.resid + off + 4);
            }
        };
        auto fbFin = [&](FB& f, int buf) {
            char* base = lds + buf * BUF;
#pragma unroll
            for (int j = 0; j < AR; ++j) {
                int row = j * 32 + srow8;
                int n = m0 + row;
                size_t off = ((size_t)b * Np + n) * 256 + f.k0 + sgran * 8;
                bool real = (n < NcT);
                float fu[8];
                fu[0] = real ? f.r0[j].x + fmaf(bf2f(f.ov[j][0]), f.s0.x, f.h0.x) : 0.f;
                fu[1] = real ? f.r0[j].y + fmaf(bf2f(f.ov[j][1]), f.s0.y, f.h0.y) : 0.f;
                fu[2] = real ? f.r0[j].z + fmaf(bf2f(f.ov[j][2]), f.s0.z, f.h0.z) : 0.f;
                fu[3] = real ? f.r0[j].w + fmaf(bf2f(f.ov[j][3]), f.s0.w, f.h0.w) : 0.f;
                fu[4] = real ? f.r1[j].x + fmaf(bf2f(f.ov[j][4]), f.s1.x, f.h1.x) : 0.f;
                fu[5] = real ? f.r1[j].y + fmaf(bf2f(f.ov[j][5]), f.s1.y, f.h1.y) : 0.f;
                fu[6] = real ? f.r1[j].z + fmaf(bf2f(f.ov[j][6]), f.s1.z, f.h1.z) : 0.f;
                fu[7] = real ? f.r1[j].w + fmaf(bf2f(f.ov[j][7]), f.s1.w, f.h1.w) : 0.f;
                float4 w0, w1;
                w0.x = fu[0]; w0.y = fu[1]; w0.z = fu[2]; w0.w = fu[3];
                w1.x = fu[4]; w1.y = fu[5]; w1.z = fu[6]; w1.w = fu[7];
                *(float4*)(p.resid + off) = w0;
                *(float4*)(p.resid + off + 4) = w1;
                u16x8 hv;
#pragma unroll
                for (int i = 0; i < 8; ++i) hv[i] = f2bf(fu[i]);
                *(u16x8*)(base + row * 128 + ((sgran ^ (row & 7)) << 4)) = hv;
            }
        };

        fbIssue(fA, kstart);        stageB1(0, kstart);
        fbIssue(fB, kstart + 64);   stageB1(1, kstart + 64);
        VMC(14);
        fbFin(fA, 0);
        fbIssue(fA, kstart + 128);  stageB1(2, kstart + 128);
        LGKM0();
        __builtin_amdgcn_s_barrier();
        __builtin_amdgcn_sched_barrier(0);
        compute(0);
        VMC(18);
        fbFin(fB, 1);
        fbIssue(fB, kstart + 192);  stageB1(3, kstart + 192);
        LGKM0();
        __builtin_amdgcn_s_barrier();
        __builtin_amdgcn_sched_barrier(0);
        compute(1);
        VMC(18);
        fbFin(fA, 2);
        LGKM0();
        __builtin_amdgcn_s_barrier();
        __builtin_amdgcn_sched_barrier(0);
        compute(2);
        VMC(4);
        fbFin(fB, 3);
        LGKM0();
        __builtin_amdgcn_s_barrier();
        __builtin_amdgcn_sched_barrier(0);
        compute(3);
        __syncthreads();
    } else {
        const int nsteps1 = (SPLITK ? p.kchunk : p.K) >> 6;
        const int spl2 = DUALK ? (p.K2 >> 6) : 0;
        const int loop1 = p.nsl * nsteps1;
        const int tot = loop1 + spl2;

        const unsigned short* Ab2 = DUALK ?
            (p.A2 + (size_t)b * p.aB2 + (size_t)m0 * p.lda2) : nullptr;
        const unsigned short* Bb2 = DUALK ?
            (p.B2 + (size_t)b * p.bB2 + (size_t)n0 * p.ldb2) : nullptr;
        auto stage2 = [&](int buf, int k0) {
            if constexpr (DUALK) {
                char* base = lds + buf * BUF;
                const unsigned short* As = Ab2 + k0 + sswz;
#pragma unroll
                for (int j = 0; j < AR; ++j)
                    __builtin_amdgcn_global_load_lds(
                        (const __attribute__((address_space(1))) void*)
                            (As + (size_t)(j * 32 + srow8) * p.lda2),
                        (__attribute__((address_space(3))) void*)(base + j * 4096 + tid * 16),
                        16, 0, 0);
                const unsigned short* Bs = Bb2 + k0 + sswz;
#pragma unroll
                for (int j = 0; j < 4; ++j)
                    __builtin_amdgcn_global_load_lds(
                        (const __attribute__((address_space(1))) void*)
                            (Bs + (size_t)(j * 32 + srow8) * p.ldb2),
                        (__attribute__((address_space(3))) void*)(base + TBA + j * 4096 + tid * 16),
                        16, 0, 0);
            }
        };

        auto stage_g = [&](int buf, int g) {
            if (g < loop1) {
                int sl = g / nsteps1;
                int st = g - sl * nsteps1;
                stage1(buf, sl, kstart + (st << 6));
            } else {
                stage2(buf, (g - loop1) << 6);
            }
        };

        stage_g(0, 0);
        if (1 < tot) stage_g(1, 1);
        if (2 < tot) stage_g(2, 2);
        for (int gs = 0; gs < tot; ++gs) {
            if constexpr (MT == 64) {
                if (gs + 2 < tot) VMC(12);
                else if (gs + 1 < tot) VMC(6);
                else VMC(0);
            } else {
                if (gs + 2 < tot) VMC(16);
                else if (gs + 1 < tot) VMC(8);
                else VMC(0);
            }
            __builtin_amdgcn_s_barrier();
            __builtin_amdgcn_sched_barrier(0);
            if (gs + 3 < tot) stage_g((gs + 3) & 3, gs + 3);
            compute(gs & 3);
            if constexpr (DUALK) {
                if (gs == loop1 - 1) {
#pragma unroll
                    for (int r = 0; r < 4; ++r) {
#pragma unroll
                        for (int c = 0; c < NB; ++c) {
                            acc[r][c][0] *= dvv[r].x;
                            acc[r][c][1] *= dvv[r].y;
                            acc[r][c][2] *= dvv[r].z;
                            acc[r][c][3] *= dvv[r].w;
                        }
                    }
                }
            }
        }
        __syncthreads();
    }

    // stage accumulators to LDS f32 [MT][132]
    float* ot = (float*)lds;
    {
        const int lo = l & 15, gq = l >> 4;
#pragma unroll
        for (int r = 0; r < 4; ++r)
#pragma unroll
            for (int c = 0; c < NB; ++c)
#pragma unroll
                for (int j = 0; j < 4; ++j) {
                    float v = acc[r][c][j];
                    if (EPI == 1) v = fmaxf(v, 0.f);
                    ot[(wr * 64 + r * 16 + gq * 4 + j) * 132 +
                       wc * (16 * NB) + c * 16 + lo] = v;
                }
    }
    __syncthreads();

    {   // row-major store
        constexpr int TPR = 256 / MT;
        const int r = tid / TPR;
        const int c0 = (tid % TPR) * (MT / 2);
        const int m0s = XORM ? (m0 ^ 128) : m0;
        unsigned short* dst = p.outSM + (size_t)b * p.smB + smOff +
                              (size_t)(m0s + r) * p.ldsm + n0 + c0;
#pragma unroll
        for (int k = 0; k < MT / 16; ++k) {
            u16x8 o;
#pragma unroll
            for (int j = 0; j < 8; ++j) o[j] = f2bf(ot[r * 132 + c0 + 8 * k + j]);
            *(u16x8*)(dst + 8 * k) = o;
        }
    }

    if (CMOUT) {
        const int c = tid >> 1, r0 = (tid & 1) * (MT / 2);
        const float* dv = p.dinv + (size_t)b * Np + m0 + r0;
        unsigned short* dst = p.outCM + (size_t)b * p.cmB +
                              (size_t)(n0 + c) * Np + m0 + r0;
#pragma unroll
        for (int k = 0; k < MT / 16; ++k) {
            u16x8 o;
#pragma unroll
            for (int j = 0; j < 8; ++j) {
                float v = ot[(r0 + 8 * k + j) * 132 + c];
                if (CMOUT == 2) v *= dv[8 * k + j];
                o[j] = f2bf(v);
            }
            *(u16x8*)(dst + 8 * k) = o;
        }
    }

    if (BNSTAT) {
        float* p1 = (float*)(lds + OTB);
        float* p2 = p1 + 256;
        const int col = tid & 127, half = tid >> 7;
        float s = 0.f, s2 = 0.f;
#pragma unroll
        for (int i = 0; i < MT / 2; ++i) {
            float v = ot[(half * (MT / 2) + i) * 132 + col];
            s += v;
            if (BNSTAT == 2) s2 = fmaf(v, v, s2);
        }
        p1[half * 128 + col] = s;
        if (BNSTAT == 2) p2[half * 128 + col] = s2;
        __syncthreads();
        if (tid < 128) {
            float aa = p1[tid] + p1[128 + tid];
            size_t slot = ((size_t)b * MY + by) * 256 + n0 + tid;
            p.ps[slot] = aa;
            if (BNSTAT == 2) p.ps2[slot] = p2[tid] + p2[128 + tid];
        }
    }
    __syncthreads();   // LDS safe for next phase
}

// BN finalize body: 16 blocks x 16 channels; 100 partial groups
__device__ void bnfin_body(char* ldsb, int bid,
                           const float* __restrict__ ps,
                           const float* __restrict__ ps2,
                           const float* __restrict__ gamma,
                           const float* __restrict__ beta,
                           float* __restrict__ scale, float* __restrict__ shift)
{
    float* l1 = (float*)ldsb;
    float* l2 = l1 + 256;
    int t = threadIdx.x;
    int c = bid * 16 + (t & 15);
    int gl = t >> 4;
    float a = 0.f, a2 = 0.f;
    for (int g = gl; g < 100; g += 16) {
        a += ps[(size_t)g * 256 + c];
        a2 += ps2[(size_t)g * 256 + c];
    }
    l1[t] = a; l2[t] = a2;
    __syncthreads();
    if (gl == 0) {
#pragma unroll
        for (int j = 1; j < 16; ++j) {
            a += l1[j * 16 + (t & 15)];
            a2 += l2[j * 16 + (t & 15)];
        }
        const float inv = 1.f / (float)(Bc * NcT);
        float mean = a * inv;
        float var = a2 * inv - mean * mean;
        float sc = gamma[c] * rsqrtf(var + EPSc);
        scale[c] = sc;
        shift[c] = beta[c] - mean * sc;
    }
}

// standalone mgemm wrapper (used for the U projection only)
template <int MT, int EPI, int CMOUT, bool SPLITK, int BNSTAT, bool FUSEBN,
          bool XORM, bool DUALK>
__global__ __launch_bounds__(256) void mgemm_g(GP p)
{
    constexpr int TBA = MT * 64 * 2;
    constexpr int BUF = TBA + 128 * 64 * 2;
    constexpr int OTB = MT * 132 * 4;
    constexpr int LDSZ = (4 * BUF > OTB + 2048) ? 4 * BUF : (OTB + 2048);
    __shared__ __align__(16) char lds[LDSZ];
    gemm_body<MT, EPI, CMOUT, SPLITK, BNSTAT, FUSEBN, XORM, DUALK>(
        lds, blockIdx.x, blockIdx.y, blockIdx.z, (int)gridDim.y, p);
}

// ---------------------------------------------------------------------------
// Fused per-stage kernel: 200 blocks, manual subset barriers.
//   P1 g(200) -> P2 abt(80) -> P3 WM(32) -> P4 o(200) -> P5 bnfin(16)
// ---------------------------------------------------------------------------
struct SP {
    GP g, abt, wm, o;
    const float* ps; const float* ps2;
    const float* gammap; const float* betap;
    float* scale; float* shiftb;
    unsigned* flags;   // 4 counters, zeroed per launch
};

template <bool FIRST>
__global__ __launch_bounds__(256) void stage_k(SP sp)
{
    __shared__ __align__(16) char lds[131072];
    const int bid = blockIdx.x;

    // P1: g = Wg[s] @ out (FUSEBN applies previous stage's BN to residual)
    gemm_body<64, 0, 2, false, 0, (FIRST ? false : true), false, false>(
        lds, 0, bid % 50, bid / 50, 50, sp.g);
    signal_flag(&sp.flags[0]);

    // P2: abt split-K partials
    if (bid < 80) {
        wait_flag(&sp.flags[0], 200);
        gemm_body<64, 0, 0, true, 0, false, true, false>(
            lds, 0, bid % 4, bid / 4, 4, sp.abt);
        signal_flag(&sp.flags[1]);
    }
    // P3: WM = W1 @ Mst (slice-accumulating Cpart)
    if (bid < 32) {
        wait_flag(&sp.flags[1], 80);
        gemm_body<64, 0, 0, false, 0, false, false, false>(
            lds, bid % 2, (bid / 2) % 4, bid / 8, 4, sp.wm);
        signal_flag(&sp.flags[2]);
    }
    // P4: o = (U @ WM^T)*0.5*dinv + g @ W2^T + BN partial stats
    wait_flag(&sp.flags[2], 32);
    gemm_body<128, 0, 0, false, 2, false, false, true>(
        lds, bid % 2, (bid / 2) % 25, bid / 50, 25, sp.o);
    signal_flag(&sp.flags[3]);

    // P5: BN finalize -> scale/shift for next stage
    if (bid < 16) {
        wait_flag(&sp.flags[3], 200);
        bnfin_body(lds, bid, sp.ps, sp.ps2, sp.gammap, sp.betap,
                   sp.scale, sp.shiftb);
    }
}

// ---------------------------------------------------------------------------
// prep: weight f32->bf16 (544 items) + input transpose (800 items)
// ---------------------------------------------------------------------------
__global__ __launch_bounds__(256) void prep_k(
    const float* __restrict__ x, const float* __restrict__ Wt,
    const float* __restrict__ Wp, const float* __restrict__ Wg,
    const float* __restrict__ W1, const float* __restrict__ W2,
    unsigned short* __restrict__ Wcomb, unsigned short* __restrict__ Wgh,
    unsigned short* __restrict__ W1h, unsigned short* __restrict__ W2h,
    float* __restrict__ out_sm, unsigned short* __restrict__ outh)
{
    __shared__ float tb[64][65];
    int item = blockIdx.x;
    int t = threadIdx.x;
    if (item < 544) {
        size_t e = ((size_t)item * 256 + t) * 4;
        const float* src; unsigned short* dst;
        if (e < 32768)       { src = Wt + e;           dst = Wcomb + e; }
        else if (e < 65536)  { src = Wp + (e - 32768); dst = Wcomb + e; }
        else if (e < 229376) { size_t o = e - 65536;  src = Wg + o; dst = Wgh + o; }
        else if (e < 393216) { size_t o = e - 229376; src = W1 + o; dst = W1h + o; }
        else                 { size_t o = e - 393216; src = W2 + o; dst = W2h + o; }
        float4 v = *(const float4*)src;
        u16x4 t4;
        t4[0] = f2bf(v.x); t4[1] = f2bf(v.y); t4[2] = f2bf(v.z); t4[3] = f2bf(v.w);
        *(u16x4*)dst = t4;
        return;
    }
    int it = item - 544;
    int nx = it % 50, cy = (it / 50) % 4, b = it / 200;
    int c0 = cy * 64, n0 = nx * 64;
    const bool pad = (n0 >= NcT);
    if (!pad) {
        int ci = t >> 2, nb = (t & 3) * 16;
        const float* src = x + ((size_t)b * Cc + c0 + ci) * NcT + n0 + nb;
#pragma unroll
        for (int k = 0; k < 4; ++k) {
            float4 v = *(const float4*)(src + 4 * k);
            tb[ci][nb + 4 * k + 0] = v.x; tb[ci][nb + 4 * k + 1] = v.y;
            tb[ci][nb + 4 * k + 2] = v.z; tb[ci][nb + 4 * k + 3] = v.w;
        }
    }
    __syncthreads();
    int r = t >> 2, cb = (t & 3) * 16;
    size_t off = ((size_t)b * Np + n0 + r) * 256 + c0 + cb;
    float vv[16];
#pragma unroll
    for (int j = 0; j < 16; ++j) vv[j] = pad ? 0.f : tb[cb + j][r];
    float* dst = out_sm + off;
#pragma unroll
    for (int k = 0; k < 4; ++k) {
        float4 v; v.x = vv[4*k]; v.y = vv[4*k+1]; v.z = vv[4*k+2]; v.w = vv[4*k+3];
        *(float4*)(dst + 4 * k) = v;
    }
    u16x8 h1, h2;
#pragma unroll
    for (int j = 0; j < 8; ++j) { h1[j] = f2bf(vv[j]); h2[j] = f2bf(vv[8 + j]); }
    unsigned short* dh = outh + off;
    *(u16x8*)dh = h1;
    *(u16x8*)(dh + 8) = h2;
}

// dinv[b][i] = d>0 ? rsqrt(d) : 0, d = 0.5*sum_q U[b][i][q]*rs[b][q^128]
__global__ __launch_bounds__(256) void dinv_k(
    const unsigned short* __restrict__ U, const float* __restrict__ rp,
    float* __restrict__ dinv)
{
    __shared__ float rsl[256];
    int b = blockIdx.y, tid = threadIdx.x;
    float s = 0.f;
    for (int j = 0; j < 25; ++j) s += rp[((size_t)b * 25 + j) * 256 + tid];
    rsl[tid ^ 128] = s;
    __syncthreads();
    int i = blockIdx.x * 256 + tid;
    if (i < Np) {
        const unsigned short* row = U + ((size_t)b * Np + i) * 256;
        float acc = 0.f;
        for (int q0 = 0; q0 < 256; q0 += 8) {
            u16x8 v = *(const u16x8*)(row + q0);
#pragma unroll
            for (int j = 0; j < 8; ++j) acc = fmaf(bf2f(v[j]), rsl[q0 + j], acc);
        }
        float d = 0.5f * acc;
        dinv[(size_t)b * Np + i] = d > 0.f ? rsqrtf(d) : 0.f;
    }
}

// d_out[b][c][n] = transpose(out_sm + BN(o_sm))   (final stage fused)
__global__ __launch_bounds__(256) void xpoutbn_k(
    const float* __restrict__ out_sm, const unsigned short* __restrict__ oin,
    const float* __restrict__ scale, const float* __restrict__ shift,
    float* __restrict__ outp)
{
    __shared__ float tb[64][65];
    __shared__ float lsc[64], lsh[64];
    int b = blockIdx.z, c0 = blockIdx.y * 64, n0 = blockIdx.x * 64;
    int t = threadIdx.x;
    if (t < 64) { lsc[t] = scale[c0 + t]; lsh[t] = shift[c0 + t]; }
    __syncthreads();
    {
        int r = t >> 2, cb = (t & 3) * 16;
        size_t off = ((size_t)b * Np + n0 + r) * 256 + c0 + cb;
#pragma unroll
        for (int k = 0; k < 2; ++k) {
            float4 a0 = *(const float4*)(out_sm + off + 8 * k);
            float4 a1 = *(const float4*)(out_sm + off + 8 * k + 4);
            u16x8 ov = *(const u16x8*)(oin + off + 8 * k);
            tb[r][cb + 8*k + 0] = a0.x + fmaf(bf2f(ov[0]), lsc[cb + 8*k + 0], lsh[cb + 8*k + 0]);
            tb[r][cb + 8*k + 1] = a0.y + fmaf(bf2f(ov[1]), lsc[cb + 8*k + 1], lsh[cb + 8*k + 1]);
            tb[r][cb + 8*k + 2] = a0.z + fmaf(bf2f(ov[2]), lsc[cb + 8*k + 2], lsh[cb + 8*k + 2]);
            tb[r][cb + 8*k + 3] = a0.w + fmaf(bf2f(ov[3]), lsc[cb + 8*k + 3], lsh[cb + 8*k + 3]);
            tb[r][cb + 8*k + 4] = a1.x + fmaf(bf2f(ov[4]), lsc[cb + 8*k + 4], lsh[cb + 8*k + 4]);
            tb[r][cb + 8*k + 5] = a1.y + fmaf(bf2f(ov[5]), lsc[cb + 8*k + 5], lsh[cb + 8*k + 5]);
            tb[r][cb + 8*k + 6] = a1.z + fmaf(bf2f(ov[6]), lsc[cb + 8*k + 6], lsh[cb + 8*k + 6]);
            tb[r][cb + 8*k + 7] = a1.w + fmaf(bf2f(ov[7]), lsc[cb + 8*k + 7], lsh[cb + 8*k + 7]);
        }
    }
    __syncthreads();
    {
        int c = t >> 2, rb = (t & 3) * 16;
        float vv[16];
#pragma unroll
        for (int j = 0; j < 16; ++j) vv[j] = tb[rb + j][c];
        float* dst = outp + ((size_t)b * Cc + c0 + c) * NcT + n0 + rb;
#pragma unroll
        for (int k = 0; k < 4; ++k) {
            float4 v; v.x = vv[4*k]; v.y = vv[4*k+1]; v.z = vv[4*k+2]; v.w = vv[4*k+3];
            *(float4*)(dst + 4 * k) = v;
        }
    }
}

}  // namespace

extern "C" void kernel_launch(void* const* d_in, const int* in_sizes, int n_in,
                              void* d_out, int out_size, void* d_ws, size_t ws_size,
                              hipStream_t stream) {
    const float* x     = (const float*)d_in[0];
    const float* Wt    = (const float*)d_in[1];
    const float* Wp    = (const float*)d_in[2];
    const float* Wg    = (const float*)d_in[3];
    const float* W1    = (const float*)d_in[4];
    const float* W2    = (const float*)d_in[5];
    const float* gamma = (const float*)d_in[6];
    const float* beta  = (const float*)d_in[7];

    char* p = (char*)d_ws;
    auto alloc = [&](size_t bytes) { char* r = p; p += (bytes + 255) & ~(size_t)255; return r; };
    float*          out_sm = (float*)         alloc((size_t)Bc * Np * 256 * 4);
    unsigned short* outh   = (unsigned short*)alloc((size_t)Bc * Np * 256 * 2);
    unsigned short* U_sm   = (unsigned short*)alloc((size_t)Bc * Np * 256 * 2);
    unsigned short* U_cm   = (unsigned short*)alloc((size_t)Bc * 256 * Np * 2);
    unsigned short* g_sm   = (unsigned short*)alloc((size_t)Bc * Np * Pc * 2);
    unsigned short* g_cmd  = (unsigned short*)alloc((size_t)Bc * Pc * Np * 2);
    unsigned short* o_sm   = (unsigned short*)alloc((size_t)Bc * Np * 256 * 2);
    unsigned short* Cpart  = (unsigned short*)alloc((size_t)KSn * Bc * 256 * Pc * 2);
    unsigned short* WMb    = (unsigned short*)alloc((size_t)Bc * Cc * 256 * 2);
    unsigned short* Wcomb  = (unsigned short*)alloc((size_t)Cc * Cc * 2);
    unsigned short* Wgh    = (unsigned short*)alloc((size_t)Sc * Pc * Cc * 2);
    unsigned short* W1h    = (unsigned short*)alloc((size_t)Sc * Cc * Pc * 2);
    unsigned short* W2h    = (unsigned short*)alloc((size_t)Sc * Cc * Pc * 2);
    float*          rp     = (float*)         alloc((size_t)100 * 256 * 4);
    float*          dinv   = (float*)         alloc((size_t)Bc * Np * 4);
    float*          ps     = (float*)         alloc((size_t)100 * 256 * 4);
    float*          ps2    = (float*)         alloc((size_t)100 * 256 * 4);
    float*          scale  = (float*)         alloc(256 * 4);
    float*          shiftb = (float*)         alloc(256 * 4);
    unsigned*       flags  = (unsigned*)      alloc(Sc * 4 * sizeof(unsigned));

    const long NpC = (long)Np * 256;
    dim3 blk(256);

    (void)hipMemsetAsync(flags, 0, Sc * 4 * sizeof(unsigned), stream);

    prep_k<<<1344, blk, 0, stream>>>(x, Wt, Wp, Wg, W1, W2,
                                     Wcomb, Wgh, W1h, W2h, out_sm, outh);

    // U = relu([Wt;Wp] @ x): spatial-major + col-major + col sums
    {
        GP g{};
        g.A = outh; g.lda = 256; g.aB = NpC; g.aSl = 0;
        g.Bw = Wcomb; g.ldb = 256; g.bB = 0; g.bSl = 0;
        g.K = 256; g.nsl = 1;
        g.outSM = U_sm; g.ldsm = 256; g.smB = NpC; g.smSlice = 0;
        g.outCM = U_cm; g.cmB = (long)256 * Np;
        g.ps = rp;
        mgemm_g<128, 1, 1, false, 1, false, false, false>
            <<<dim3(2, 25, Bc), blk, 0, stream>>>(g);
    }

    dinv_k<<<dim3(13, Bc), blk, 0, stream>>>(U_sm, rp, dinv);

    for (int s = 0; s < Sc; ++s) {
        SP sp{};
        // P1: g
        sp.g.A = outh; sp.g.lda = 256; sp.g.aB = NpC; sp.g.aSl = 0;
        sp.g.Bw = Wgh + (size_t)s * Pc * Cc; sp.g.ldb = 256; sp.g.bB = 0; sp.g.bSl = 0;
        sp.g.K = 256; sp.g.nsl = 1;
        sp.g.outSM = g_sm; sp.g.ldsm = 128; sp.g.smB = (long)Np * 128; sp.g.smSlice = 0;
        sp.g.outCM = g_cmd; sp.g.cmB = (long)Pc * Np;
        sp.g.dinv = dinv;
        sp.g.oin = o_sm; sp.g.bnsc = scale; sp.g.bnsh = shiftb; sp.g.resid = out_sm;
        // P2: abt
        sp.abt.A = U_cm; sp.abt.lda = Np; sp.abt.aB = (long)256 * Np; sp.abt.aSl = 0;
        sp.abt.Bw = g_cmd; sp.abt.ldb = Np; sp.abt.bB = (long)Pc * Np; sp.abt.bSl = 0;
        sp.abt.K = Np; sp.abt.kchunk = KCH; sp.abt.nsl = 1;
        sp.abt.outSM = Cpart; sp.abt.ldsm = 128; sp.abt.smB = (long)256 * Pc;
        sp.abt.smSlice = (long)Bc * 256 * Pc;
        // P3: WM
        sp.wm.A = W1h + (size_t)s * Cc * Pc; sp.wm.lda = 128; sp.wm.aB = 0; sp.wm.aSl = 0;
        sp.wm.Bw = Cpart; sp.wm.ldb = 128; sp.wm.bB = (long)256 * Pc;
        sp.wm.bSl = (long)Bc * 256 * Pc;
        sp.wm.K = 128; sp.wm.nsl = KSn;
        sp.wm.outSM = WMb; sp.wm.ldsm = 256; sp.wm.smB = (long)Cc * 256; sp.wm.smSlice = 0;
        // P4: o
        sp.o.A = U_sm; sp.o.lda = 256; sp.o.aB = NpC; sp.o.aSl = 0;
        sp.o.Bw = WMb; sp.o.ldb = 256; sp.o.bB = (long)Cc * 256; sp.o.bSl = 0;
        sp.o.K = 256; sp.o.nsl = 1;
        sp.o.A2 = g_sm; sp.o.lda2 = 128; sp.o.aB2 = (long)Np * 128;
        sp.o.B2 = W2h + (size_t)s * Cc * Pc; sp.o.ldb2 = 128; sp.o.bB2 = 0;
        sp.o.K2 = 128;
        sp.o.outSM = o_sm; sp.o.ldsm = 256; sp.o.smB = NpC; sp.o.smSlice = 0;
        sp.o.ps = ps; sp.o.ps2 = ps2;
        sp.o.dinv = dinv;
        // P5: bnfin
        sp.ps = ps; sp.ps2 = ps2;
        sp.gammap = gamma + (size_t)s * Cc;
        sp.betap = beta + (size_t)s * Cc;
        sp.scale = scale; sp.shiftb = shiftb;
        sp.flags = flags + s * 4;

        if (s == 0) stage_k<true><<<200, blk, 0, stream>>>(sp);
        else        stage_k<false><<<200, blk, 0, stream>>>(sp);
    }

    // final: d_out = transpose(out_sm + BN(o_sm))
    xpoutbn_k<<<dim3(49, 4, Bc), blk, 0, stream>>>(out_sm, o_sm, scale, shiftb,
                                                   (float*)d_out);
}

// Round 16
// 373.322 us; speedup vs baseline: 1.3620x; 1.1176x over previous
//
#include <hip/hip_runtime.h>

#define VMC(n) asm volatile("s_waitcnt vmcnt(" #n ")" ::: "memory")
#define LGKM0() asm volatile("s_waitcnt lgkmcnt(0)" ::: "memory")

namespace {

constexpr int Bc = 4;
constexpr int Cc = 256;
constexpr int Pc = 128;
constexpr int NcT = 3136;  // true spatial size 56*56
constexpr int Np = 3200;   // padded to 25*128
constexpr int Sc = 5;
constexpr int KSn = 5;     // split-K chunks for abt (3200 = 5*640)
constexpr int KCH = 640;
constexpr float EPSc = 1e-5f;

typedef __attribute__((ext_vector_type(8))) short bf16x8;
typedef __attribute__((ext_vector_type(4))) float f32x4;
typedef __attribute__((ext_vector_type(8))) unsigned short u16x8;
typedef __attribute__((ext_vector_type(4))) unsigned short u16x4;

__device__ inline float bf2f(unsigned short u) {
    return __uint_as_float(((unsigned)u) << 16);
}
__device__ inline unsigned short f2bf(float f) {
    unsigned u = __float_as_uint(f);
    return (unsigned short)((u + 0x7FFFu + ((u >> 16) & 1u)) >> 16);
}

struct GP {
    const unsigned short* A; int lda; long aB; long aSl;
    const unsigned short* Bw; int ldb; long bB; long bSl;
    const unsigned short* A2; int lda2; long aB2;
    const unsigned short* B2; int ldb2; long bB2;
    int K; int K2; int nsl; int kchunk;
    unsigned short* outSM; int ldsm; long smB; long smSlice;
    unsigned short* outCM; long cmB;
    float* ps; float* ps2;
    const float* bnsc; const float* bnsh;   // FUSEBN precomputed scale/shift
    const float* dinv;
    const unsigned short* oin;
    float* resid;
    // BNSTAT==2 last-block finalize:
    unsigned* cnt; const float* gammap; const float* betap;
    float* osc; float* osh;
};

// ---------------------------------------------------------------------------
// MFMA GEMM: D[m][n] = sum over slices/loops of A[m][k]*B[n][k] (K-contig).
// Tile MT(m) x 128(n), 4 waves, K-step 64. Non-FUSEBN: 4-buffer depth-3
// pipeline with counted vmcnt + raw s_barrier. FUSEBN: explicit 4-step
// (K=256) depth-2 register-prefetch pipeline.
// EPI: 0 none, 1 relu.  CMOUT: 0 none, 1 plain col-major, 2 col-major*dinv[m]
// SPLITK: z=ks*4+b.  BNSTAT 2: col sums+sumsq -> ps/ps2, then LAST block
// (atomic ticket) reduces them to scale/shift (no polling, wait-free).
// XORM: row-major store to (m0^128)+r.  DUALK: 2nd loop (A2,B2); acc scaled
// by 0.5*dinv[m] between loops.
// ---------------------------------------------------------------------------
template <int MT, int EPI, int CMOUT, bool SPLITK, int BNSTAT, bool FUSEBN,
          bool XORM, bool DUALK>
__global__ __launch_bounds__(256) void mgemm(GP p)
{
    constexpr int TBA = MT * 64 * 2;
    constexpr int TBB = 128 * 64 * 2;
    constexpr int BUF = TBA + TBB;
    constexpr int OTB = MT * 132 * 4;
    constexpr int LDSZ = (4 * BUF > OTB + 2048) ? 4 * BUF : (OTB + 2048);
    __shared__ __align__(16) char lds[LDSZ];

    int b, kstart;
    long smOff;
    if (SPLITK) {
        b = blockIdx.z & 3;
        int ks = blockIdx.z >> 2;
        kstart = ks * p.kchunk;
        smOff = (long)ks * p.smSlice;
    } else {
        b = blockIdx.z; kstart = 0; smOff = 0;
    }
    const int n0 = blockIdx.x * 128;
    const int m0 = blockIdx.y * MT;
    const int tid = threadIdx.x;
    const int w = tid >> 6, l = tid & 63;

    const unsigned short* Ab = p.A + (size_t)b * p.aB + (size_t)m0 * p.lda;
    const unsigned short* Bb = p.Bw + (size_t)b * p.bB + (size_t)n0 * p.ldb;

    const int srow8 = tid >> 3;                  // 0..31
    const int sgran = tid & 7;
    const int sswz = (sgran ^ (srow8 & 7)) * 8;  // swizzled source granule
    constexpr int AR = MT / 32;                  // A staging rounds

    constexpr int WC = (MT == 128) ? 2 : 4;      // waves along n
    constexpr int NB = 128 / WC / 16;            // B frags per wave
    const int wr = w / WC, wc = w % WC;

    f32x4 acc[4][NB] = {};

    float4 dvv[4];
    if constexpr (DUALK) {
#pragma unroll
        for (int r = 0; r < 4; ++r) {
            float4 v = *(const float4*)(p.dinv + (size_t)b * Np + m0 +
                                        wr * 64 + r * 16 + (l >> 4) * 4);
            v.x *= 0.5f; v.y *= 0.5f; v.z *= 0.5f; v.w *= 0.5f;
            dvv[r] = v;
        }
    }

    auto stage1 = [&](int buf, int sl, int k0) {
        char* base = lds + buf * BUF;
        const unsigned short* As = Ab + (size_t)sl * p.aSl + k0 + sswz;
#pragma unroll
        for (int j = 0; j < AR; ++j)
            __builtin_amdgcn_global_load_lds(
                (const __attribute__((address_space(1))) void*)
                    (As + (size_t)(j * 32 + srow8) * p.lda),
                (__attribute__((address_space(3))) void*)(base + j * 4096 + tid * 16),
                16, 0, 0);
        const unsigned short* Bs = Bb + (size_t)sl * p.bSl + k0 + sswz;
#pragma unroll
        for (int j = 0; j < 4; ++j)
            __builtin_amdgcn_global_load_lds(
                (const __attribute__((address_space(1))) void*)
                    (Bs + (size_t)(j * 32 + srow8) * p.ldb),
                (__attribute__((address_space(3))) void*)(base + TBA + j * 4096 + tid * 16),
                16, 0, 0);
    };

    auto stageB1 = [&](int buf, int k0) {
        char* base = lds + buf * BUF + TBA;
        const unsigned short* Bs = Bb + k0 + sswz;
#pragma unroll
        for (int j = 0; j < 4; ++j)
            __builtin_amdgcn_global_load_lds(
                (const __attribute__((address_space(1))) void*)
                    (Bs + (size_t)(j * 32 + srow8) * p.ldb),
                (__attribute__((address_space(3))) void*)(base + j * 4096 + tid * 16),
                16, 0, 0);
    };

    auto compute = [&](int buf) {
        const char* base = lds + buf * BUF;
        const int lo = l & 15, gq = l >> 4;
#pragma unroll
        for (int kh = 0; kh < 2; ++kh) {
            const int lg = kh * 4 + gq;
            bf16x8 bf[NB];
#pragma unroll
            for (int c = 0; c < NB; ++c) {
                int brow = wc * (16 * NB) + c * 16 + lo;
                bf[c] = *(const bf16x8*)(base + TBA + brow * 128 +
                                         ((lg ^ (brow & 7)) << 4));
            }
#pragma unroll
            for (int r = 0; r < 4; ++r) {
                int arow = wr * 64 + r * 16 + lo;
                bf16x8 af = *(const bf16x8*)(base + arow * 128 +
                                             ((lg ^ (arow & 7)) << 4));
#pragma unroll
                for (int c = 0; c < NB; ++c)
                    acc[r][c] = __builtin_amdgcn_mfma_f32_16x16x32_bf16(
                        af, bf[c], acc[r][c], 0, 0, 0);
            }
        }
    };

    if constexpr (FUSEBN) {
        struct FB {
            u16x8 ov[AR]; float4 r0[AR], r1[AR];
            float4 s0, s1, h0, h1; int k0;
        };
        FB fA, fB;
        auto fbIssue = [&](FB& f, int k0) {   // 10 vm loads
            f.k0 = k0;
            f.s0 = *(const float4*)(p.bnsc + k0 + sgran * 8);
            f.s1 = *(const float4*)(p.bnsc + k0 + sgran * 8 + 4);
            f.h0 = *(const float4*)(p.bnsh + k0 + sgran * 8);
            f.h1 = *(const float4*)(p.bnsh + k0 + sgran * 8 + 4);
#pragma unroll
            for (int j = 0; j < AR; ++j) {
                size_t off = ((size_t)b * Np + (m0 + j * 32 + srow8)) * 256 +
                             k0 + sgran * 8;
                f.ov[j] = *(const u16x8*)(p.oin + off);
                f.r0[j] = *(const float4*)(p.resid + off);
                f.r1[j] = *(const float4*)(p.resid + off + 4);
            }
        };
        auto fbFin = [&](FB& f, int buf) {    // 4 vm stores + AR ds_writes
            char* base = lds + buf * BUF;
#pragma unroll
            for (int j = 0; j < AR; ++j) {
                int row = j * 32 + srow8;
                int n = m0 + row;
                size_t off = ((size_t)b * Np + n) * 256 + f.k0 + sgran * 8;
                bool real = (n < NcT);
                float fu[8];
                fu[0] = real ? f.r0[j].x + fmaf(bf2f(f.ov[j][0]), f.s0.x, f.h0.x) : 0.f;
                fu[1] = real ? f.r0[j].y + fmaf(bf2f(f.ov[j][1]), f.s0.y, f.h0.y) : 0.f;
                fu[2] = real ? f.r0[j].z + fmaf(bf2f(f.ov[j][2]), f.s0.z, f.h0.z) : 0.f;
                fu[3] = real ? f.r0[j].w + fmaf(bf2f(f.ov[j][3]), f.s0.w, f.h0.w) : 0.f;
                fu[4] = real ? f.r1[j].x + fmaf(bf2f(f.ov[j][4]), f.s1.x, f.h1.x) : 0.f;
                fu[5] = real ? f.r1[j].y + fmaf(bf2f(f.ov[j][5]), f.s1.y, f.h1.y) : 0.f;
                fu[6] = real ? f.r1[j].z + fmaf(bf2f(f.ov[j][6]), f.s1.z, f.h1.z) : 0.f;
                fu[7] = real ? f.r1[j].w + fmaf(bf2f(f.ov[j][7]), f.s1.w, f.h1.w) : 0.f;
                float4 w0, w1;
                w0.x = fu[0]; w0.y = fu[1]; w0.z = fu[2]; w0.w = fu[3];
                w1.x = fu[4]; w1.y = fu[5]; w1.z = fu[6]; w1.w = fu[7];
                *(float4*)(p.resid + off) = w0;
                *(float4*)(p.resid + off + 4) = w1;
                u16x8 hv;
#pragma unroll
                for (int i = 0; i < 8; ++i) hv[i] = f2bf(fu[i]);
                *(u16x8*)(base + row * 128 + ((sgran ^ (row & 7)) << 4)) = hv;
            }
        };

        fbIssue(fA, kstart);        stageB1(0, kstart);
        fbIssue(fB, kstart + 64);   stageB1(1, kstart + 64);
        VMC(14);
        fbFin(fA, 0);
        fbIssue(fA, kstart + 128);  stageB1(2, kstart + 128);
        LGKM0();
        __builtin_amdgcn_s_barrier();
        __builtin_amdgcn_sched_barrier(0);
        compute(0);
        VMC(18);
        fbFin(fB, 1);
        fbIssue(fB, kstart + 192);  stageB1(3, kstart + 192);
        LGKM0();
        __builtin_amdgcn_s_barrier();
        __builtin_amdgcn_sched_barrier(0);
        compute(1);
        VMC(18);
        fbFin(fA, 2);
        LGKM0();
        __builtin_amdgcn_s_barrier();
        __builtin_amdgcn_sched_barrier(0);
        compute(2);
        VMC(4);
        fbFin(fB, 3);
        LGKM0();
        __builtin_amdgcn_s_barrier();
        __builtin_amdgcn_sched_barrier(0);
        compute(3);
        __syncthreads();
    } else {
        const int nsteps1 = (SPLITK ? p.kchunk : p.K) >> 6;
        const int spl2 = DUALK ? (p.K2 >> 6) : 0;
        const int loop1 = p.nsl * nsteps1;
        const int tot = loop1 + spl2;

        const unsigned short* Ab2 = DUALK ?
            (p.A2 + (size_t)b * p.aB2 + (size_t)m0 * p.lda2) : nullptr;
        const unsigned short* Bb2 = DUALK ?
            (p.B2 + (size_t)b * p.bB2 + (size_t)n0 * p.ldb2) : nullptr;
        auto stage2 = [&](int buf, int k0) {
            if constexpr (DUALK) {
                char* base = lds + buf * BUF;
                const unsigned short* As = Ab2 + k0 + sswz;
#pragma unroll
                for (int j = 0; j < AR; ++j)
                    __builtin_amdgcn_global_load_lds(
                        (const __attribute__((address_space(1))) void*)
                            (As + (size_t)(j * 32 + srow8) * p.lda2),
                        (__attribute__((address_space(3))) void*)(base + j * 4096 + tid * 16),
                        16, 0, 0);
                const unsigned short* Bs = Bb2 + k0 + sswz;
#pragma unroll
                for (int j = 0; j < 4; ++j)
                    __builtin_amdgcn_global_load_lds(
                        (const __attribute__((address_space(1))) void*)
                            (Bs + (size_t)(j * 32 + srow8) * p.ldb2),
                        (__attribute__((address_space(3))) void*)(base + TBA + j * 4096 + tid * 16),
                        16, 0, 0);
            }
        };

        auto stage_g = [&](int buf, int g) {
            if (g < loop1) {
                int sl = g / nsteps1;
                int st = g - sl * nsteps1;
                stage1(buf, sl, kstart + (st << 6));
            } else {
                stage2(buf, (g - loop1) << 6);
            }
        };

        stage_g(0, 0);
        if (1 < tot) stage_g(1, 1);
        if (2 < tot) stage_g(2, 2);
        for (int gs = 0; gs < tot; ++gs) {
            if constexpr (MT == 64) {
                if (gs + 2 < tot) VMC(12);
                else if (gs + 1 < tot) VMC(6);
                else VMC(0);
            } else {
                if (gs + 2 < tot) VMC(16);
                else if (gs + 1 < tot) VMC(8);
                else VMC(0);
            }
            __builtin_amdgcn_s_barrier();
            __builtin_amdgcn_sched_barrier(0);
            if (gs + 3 < tot) stage_g((gs + 3) & 3, gs + 3);
            compute(gs & 3);
            if constexpr (DUALK) {
                if (gs == loop1 - 1) {   // scale loop1 accumulation by 0.5*dinv[m]
#pragma unroll
                    for (int r = 0; r < 4; ++r) {
#pragma unroll
                        for (int c = 0; c < NB; ++c) {
                            acc[r][c][0] *= dvv[r].x;
                            acc[r][c][1] *= dvv[r].y;
                            acc[r][c][2] *= dvv[r].z;
                            acc[r][c][3] *= dvv[r].w;
                        }
                    }
                }
            }
        }
        __syncthreads();
    }

    // stage accumulators to LDS f32 [MT][132]
    float* ot = (float*)lds;
    {
        const int lo = l & 15, gq = l >> 4;
#pragma unroll
        for (int r = 0; r < 4; ++r)
#pragma unroll
            for (int c = 0; c < NB; ++c)
#pragma unroll
                for (int j = 0; j < 4; ++j) {
                    float v = acc[r][c][j];
                    if (EPI == 1) v = fmaxf(v, 0.f);
                    ot[(wr * 64 + r * 16 + gq * 4 + j) * 132 +
                       wc * (16 * NB) + c * 16 + lo] = v;
                }
    }
    __syncthreads();

    {   // row-major store
        constexpr int TPR = 256 / MT;
        const int r = tid / TPR;
        const int c0 = (tid % TPR) * (MT / 2);
        const int m0s = XORM ? (m0 ^ 128) : m0;
        unsigned short* dst = p.outSM + (size_t)b * p.smB + smOff +
                              (size_t)(m0s + r) * p.ldsm + n0 + c0;
#pragma unroll
        for (int k = 0; k < MT / 16; ++k) {
            u16x8 o;
#pragma unroll
            for (int j = 0; j < 8; ++j) o[j] = f2bf(ot[r * 132 + c0 + 8 * k + j]);
            *(u16x8*)(dst + 8 * k) = o;
        }
    }

    if (CMOUT) {   // column-major store
        const int c = tid >> 1, r0 = (tid & 1) * (MT / 2);
        const float* dv = p.dinv + (size_t)b * Np + m0 + r0;
        unsigned short* dst = p.outCM + (size_t)b * p.cmB +
                              (size_t)(n0 + c) * Np + m0 + r0;
#pragma unroll
        for (int k = 0; k < MT / 16; ++k) {
            u16x8 o;
#pragma unroll
            for (int j = 0; j < 8; ++j) {
                float v = ot[(r0 + 8 * k + j) * 132 + c];
                if (CMOUT == 2) v *= dv[8 * k + j];
                o[j] = f2bf(v);
            }
            *(u16x8*)(dst + 8 * k) = o;
        }
    }

    if (BNSTAT) {
        float* p1 = (float*)(lds + OTB);
        float* p2 = p1 + 256;
        const int col = tid & 127, half = tid >> 7;
        float s = 0.f, s2 = 0.f;
#pragma unroll
        for (int i = 0; i < MT / 2; ++i) {
            float v = ot[(half * (MT / 2) + i) * 132 + col];
            s += v;
            if (BNSTAT == 2) s2 = fmaf(v, v, s2);
        }
        p1[half * 128 + col] = s;
        if (BNSTAT == 2) p2[half * 128 + col] = s2;
        __syncthreads();
        if (tid < 128) {
            float aa = p1[tid] + p1[128 + tid];
            size_t slot = ((size_t)b * gridDim.y + blockIdx.y) * 256 + n0 + tid;
            p.ps[slot] = aa;
            if (BNSTAT == 2) p.ps2[slot] = p2[tid] + p2[128 + tid];
        }
    }

    if constexpr (BNSTAT == 2) {
        // last-block BN finalize (wait-free: ticket via atomicAdd, no polling)
        __shared__ unsigned ticket;
        __threadfence();   // release: ps/ps2 visible device-wide
        __syncthreads();
        if (tid == 0)
            ticket = __hip_atomic_fetch_add(p.cnt, 1u, __ATOMIC_ACQ_REL,
                                            __HIP_MEMORY_SCOPE_AGENT);
        __syncthreads();
        const unsigned total = gridDim.x * gridDim.y * gridDim.z;
        if (ticket == total - 1) {
            __threadfence();   // acquire side
            float a = 0.f, a2 = 0.f;
            for (int g2 = 0; g2 < 100; ++g2) {
                a += p.ps[(size_t)g2 * 256 + tid];
                a2 += p.ps2[(size_t)g2 * 256 + tid];
            }
            const float inv = 1.f / (float)(Bc * NcT);
            float mean = a * inv;
            float var = a2 * inv - mean * mean;
            float sc = p.gammap[tid] * rsqrtf(var + EPSc);
            p.osc[tid] = sc;
            p.osh[tid] = p.betap[tid] - mean * sc;
        }
    }
}

// ---------------------------------------------------------------------------
// prep: weight f32->bf16 (544 items) + input transpose (800 items)
// ---------------------------------------------------------------------------
__global__ __launch_bounds__(256) void prep_k(
    const float* __restrict__ x, const float* __restrict__ Wt,
    const float* __restrict__ Wp, const float* __restrict__ Wg,
    const float* __restrict__ W1, const float* __restrict__ W2,
    unsigned short* __restrict__ Wcomb, unsigned short* __restrict__ Wgh,
    unsigned short* __restrict__ W1h, unsigned short* __restrict__ W2h,
    float* __restrict__ out_sm, unsigned short* __restrict__ outh)
{
    __shared__ float tb[64][65];
    int item = blockIdx.x;
    int t = threadIdx.x;
    if (item < 544) {
        size_t e = ((size_t)item * 256 + t) * 4;
        const float* src; unsigned short* dst;
        if (e < 32768)       { src = Wt + e;           dst = Wcomb + e; }
        else if (e < 65536)  { src = Wp + (e - 32768); dst = Wcomb + e; }
        else if (e < 229376) { size_t o = e - 65536;  src = Wg + o; dst = Wgh + o; }
        else if (e < 393216) { size_t o = e - 229376; src = W1 + o; dst = W1h + o; }
        else                 { size_t o = e - 393216; src = W2 + o; dst = W2h + o; }
        float4 v = *(const float4*)src;
        u16x4 t4;
        t4[0] = f2bf(v.x); t4[1] = f2bf(v.y); t4[2] = f2bf(v.z); t4[3] = f2bf(v.w);
        *(u16x4*)dst = t4;
        return;
    }
    int it = item - 544;
    int nx = it % 50, cy = (it / 50) % 4, b = it / 200;
    int c0 = cy * 64, n0 = nx * 64;
    const bool pad = (n0 >= NcT);
    if (!pad) {
        int ci = t >> 2, nb = (t & 3) * 16;
        const float* src = x + ((size_t)b * Cc + c0 + ci) * NcT + n0 + nb;
#pragma unroll
        for (int k = 0; k < 4; ++k) {
            float4 v = *(const float4*)(src + 4 * k);
            tb[ci][nb + 4 * k + 0] = v.x; tb[ci][nb + 4 * k + 1] = v.y;
            tb[ci][nb + 4 * k + 2] = v.z; tb[ci][nb + 4 * k + 3] = v.w;
        }
    }
    __syncthreads();
    int r = t >> 2, cb = (t & 3) * 16;
    size_t off = ((size_t)b * Np + n0 + r) * 256 + c0 + cb;
    float vv[16];
#pragma unroll
    for (int j = 0; j < 16; ++j) vv[j] = pad ? 0.f : tb[cb + j][r];
    float* dst = out_sm + off;
#pragma unroll
    for (int k = 0; k < 4; ++k) {
        float4 v; v.x = vv[4*k]; v.y = vv[4*k+1]; v.z = vv[4*k+2]; v.w = vv[4*k+3];
        *(float4*)(dst + 4 * k) = v;
    }
    u16x8 h1, h2;
#pragma unroll
    for (int j = 0; j < 8; ++j) { h1[j] = f2bf(vv[j]); h2[j] = f2bf(vv[8 + j]); }
    unsigned short* dh = outh + off;
    *(u16x8*)dh = h1;
    *(u16x8*)(dh + 8) = h2;
}

// dinv[b][i] = d>0 ? rsqrt(d) : 0, d = 0.5*sum_q U[b][i][q]*rs[b][q^128]
__global__ __launch_bounds__(256) void dinv_k(
    const unsigned short* __restrict__ U, const float* __restrict__ rp,
    float* __restrict__ dinv)
{
    __shared__ float rsl[256];
    int b = blockIdx.y, tid = threadIdx.x;
    float s = 0.f;
    for (int j = 0; j < 25; ++j) s += rp[((size_t)b * 25 + j) * 256 + tid];
    rsl[tid ^ 128] = s;
    __syncthreads();
    int i = blockIdx.x * 256 + tid;
    if (i < Np) {
        const unsigned short* row = U + ((size_t)b * Np + i) * 256;
        float acc = 0.f;
        for (int q0 = 0; q0 < 256; q0 += 8) {
            u16x8 v = *(const u16x8*)(row + q0);
#pragma unroll
            for (int j = 0; j < 8; ++j) acc = fmaf(bf2f(v[j]), rsl[q0 + j], acc);
        }
        float d = 0.5f * acc;
        dinv[(size_t)b * Np + i] = d > 0.f ? rsqrtf(d) : 0.f;
    }
}

// d_out[b][c][n] = transpose(out_sm + BN(o_sm))   (final stage fused)
__global__ __launch_bounds__(256) void xpoutbn_k(
    const float* __restrict__ out_sm, const unsigned short* __restrict__ oin,
    const float* __restrict__ scale, const float* __restrict__ shift,
    float* __restrict__ outp)
{
    __shared__ float tb[64][65];
    __shared__ float lsc[64], lsh[64];
    int b = blockIdx.z, c0 = blockIdx.y * 64, n0 = blockIdx.x * 64;
    int t = threadIdx.x;
    if (t < 64) { lsc[t] = scale[c0 + t]; lsh[t] = shift[c0 + t]; }
    __syncthreads();
    {
        int r = t >> 2, cb = (t & 3) * 16;
        size_t off = ((size_t)b * Np + n0 + r) * 256 + c0 + cb;
#pragma unroll
        for (int k = 0; k < 2; ++k) {
            float4 a0 = *(const float4*)(out_sm + off + 8 * k);
            float4 a1 = *(const float4*)(out_sm + off + 8 * k + 4);
            u16x8 ov = *(const u16x8*)(oin + off + 8 * k);
            tb[r][cb + 8*k + 0] = a0.x + fmaf(bf2f(ov[0]), lsc[cb + 8*k + 0], lsh[cb + 8*k + 0]);
            tb[r][cb + 8*k + 1] = a0.y + fmaf(bf2f(ov[1]), lsc[cb + 8*k + 1], lsh[cb + 8*k + 1]);
            tb[r][cb + 8*k + 2] = a0.z + fmaf(bf2f(ov[2]), lsc[cb + 8*k + 2], lsh[cb + 8*k + 2]);
            tb[r][cb + 8*k + 3] = a0.w + fmaf(bf2f(ov[3]), lsc[cb + 8*k + 3], lsh[cb + 8*k + 3]);
            tb[r][cb + 8*k + 4] = a1.x + fmaf(bf2f(ov[4]), lsc[cb + 8*k + 4], lsh[cb + 8*k + 4]);
            tb[r][cb + 8*k + 5] = a1.y + fmaf(bf2f(ov[5]), lsc[cb + 8*k + 5], lsh[cb + 8*k + 5]);
            tb[r][cb + 8*k + 6] = a1.z + fmaf(bf2f(ov[6]), lsc[cb + 8*k + 6], lsh[cb + 8*k + 6]);
            tb[r][cb + 8*k + 7] = a1.w + fmaf(bf2f(ov[7]), lsc[cb + 8*k + 7], lsh[cb + 8*k + 7]);
        }
    }
    __syncthreads();
    {
        int c = t >> 2, rb = (t & 3) * 16;
        float vv[16];
#pragma unroll
        for (int j = 0; j < 16; ++j) vv[j] = tb[rb + j][c];
        float* dst = outp + ((size_t)b * Cc + c0 + c) * NcT + n0 + rb;
#pragma unroll
        for (int k = 0; k < 4; ++k) {
            float4 v; v.x = vv[4*k]; v.y = vv[4*k+1]; v.z = vv[4*k+2]; v.w = vv[4*k+3];
            *(float4*)(dst + 4 * k) = v;
        }
    }
}

}  // namespace

extern "C" void kernel_launch(void* const* d_in, const int* in_sizes, int n_in,
                              void* d_out, int out_size, void* d_ws, size_t ws_size,
                              hipStream_t stream) {
    const float* x     = (const float*)d_in[0];
    const float* Wt    = (const float*)d_in[1];
    const float* Wp    = (const float*)d_in[2];
    const float* Wg    = (const float*)d_in[3];
    const float* W1    = (const float*)d_in[4];
    const float* W2    = (const float*)d_in[5];
    const float* gamma = (const float*)d_in[6];
    const float* beta  = (const float*)d_in[7];

    char* p = (char*)d_ws;
    auto alloc = [&](size_t bytes) { char* r = p; p += (bytes + 255) & ~(size_t)255; return r; };
    float*          out_sm = (float*)         alloc((size_t)Bc * Np * 256 * 4);
    unsigned short* outh   = (unsigned short*)alloc((size_t)Bc * Np * 256 * 2);
    unsigned short* U_sm   = (unsigned short*)alloc((size_t)Bc * Np * 256 * 2);
    unsigned short* U_cm   = (unsigned short*)alloc((size_t)Bc * 256 * Np * 2);
    unsigned short* g_sm   = (unsigned short*)alloc((size_t)Bc * Np * Pc * 2);
    unsigned short* g_cmd  = (unsigned short*)alloc((size_t)Bc * Pc * Np * 2);
    unsigned short* o_sm   = (unsigned short*)alloc((size_t)Bc * Np * 256 * 2);
    unsigned short* Cpart  = (unsigned short*)alloc((size_t)KSn * Bc * 256 * Pc * 2);
    unsigned short* WMb    = (unsigned short*)alloc((size_t)Bc * Cc * 256 * 2);
    unsigned short* Wcomb  = (unsigned short*)alloc((size_t)Cc * Cc * 2);
    unsigned short* Wgh    = (unsigned short*)alloc((size_t)Sc * Pc * Cc * 2);
    unsigned short* W1h    = (unsigned short*)alloc((size_t)Sc * Cc * Pc * 2);
    unsigned short* W2h    = (unsigned short*)alloc((size_t)Sc * Cc * Pc * 2);
    float*          rp     = (float*)         alloc((size_t)100 * 256 * 4);
    float*          dinv   = (float*)         alloc((size_t)Bc * Np * 4);
    float*          ps     = (float*)         alloc((size_t)100 * 256 * 4);
    float*          ps2    = (float*)         alloc((size_t)100 * 256 * 4);
    float*          scale  = (float*)         alloc(256 * 4);
    float*          shiftb = (float*)         alloc(256 * 4);
    unsigned*       cnts   = (unsigned*)      alloc(Sc * sizeof(unsigned));

    const long NpC = (long)Np * 256;
    dim3 blk(256);

    (void)hipMemsetAsync(cnts, 0, Sc * sizeof(unsigned), stream);

    prep_k<<<1344, blk, 0, stream>>>(x, Wt, Wp, Wg, W1, W2,
                                     Wcomb, Wgh, W1h, W2h, out_sm, outh);

    // U = relu([Wt;Wp] @ x): spatial-major + col-major + col sums
    {
        GP g{};
        g.A = outh; g.lda = 256; g.aB = NpC; g.aSl = 0;
        g.Bw = Wcomb; g.ldb = 256; g.bB = 0; g.bSl = 0;
        g.K = 256; g.nsl = 1;
        g.outSM = U_sm; g.ldsm = 256; g.smB = NpC; g.smSlice = 0;
        g.outCM = U_cm; g.cmB = (long)256 * Np;
        g.ps = rp;
        mgemm<128, 1, 1, false, 1, false, false, false>
            <<<dim3(2, 25, Bc), blk, 0, stream>>>(g);
    }

    dinv_k<<<dim3(13, Bc), blk, 0, stream>>>(U_sm, rp, dinv);

    for (int s = 0; s < Sc; ++s) {
        // g = Wg[s] @ out  (FUSEBN applies previous stage's BN to residual)
        {
            GP g{};
            g.A = outh; g.lda = 256; g.aB = NpC; g.aSl = 0;
            g.Bw = Wgh + (size_t)s * Pc * Cc; g.ldb = 256; g.bB = 0; g.bSl = 0;
            g.K = 256; g.nsl = 1;
            g.outSM = g_sm; g.ldsm = 128; g.smB = (long)Np * 128; g.smSlice = 0;
            g.outCM = g_cmd; g.cmB = (long)Pc * Np;
            g.dinv = dinv;
            g.oin = o_sm; g.bnsc = scale; g.bnsh = shiftb; g.resid = out_sm;
            if (s == 0)
                mgemm<64, 0, 2, false, 0, false, false, false>
                    <<<dim3(1, 50, Bc), blk, 0, stream>>>(g);
            else
                mgemm<64, 0, 2, false, 0, true, false, false>
                    <<<dim3(1, 50, Bc), blk, 0, stream>>>(g);
        }
        // Cpart[ks][b][q^128][p] = partial_i U_cm[q][i] * g_cmd[p][i]
        {
            GP g{};
            g.A = U_cm; g.lda = Np; g.aB = (long)256 * Np; g.aSl = 0;
            g.Bw = g_cmd; g.ldb = Np; g.bB = (long)Pc * Np; g.bSl = 0;
            g.K = Np; g.kchunk = KCH; g.nsl = 1;
            g.outSM = Cpart; g.ldsm = 128; g.smB = (long)256 * Pc;
            g.smSlice = (long)Bc * 256 * Pc;
            mgemm<64, 0, 0, true, 0, false, true, false>
                <<<dim3(1, 4, KSn * Bc), blk, 0, stream>>>(g);
        }
        // WM[b][c][q] = sum_ks sum_p W1[c][p] * Cpart[ks][b][q][p]
        {
            GP g{};
            g.A = W1h + (size_t)s * Cc * Pc; g.lda = 128; g.aB = 0; g.aSl = 0;
            g.Bw = Cpart; g.ldb = 128; g.bB = (long)256 * Pc;
            g.bSl = (long)Bc * 256 * Pc;
            g.K = 128; g.nsl = KSn;
            g.outSM = WMb; g.ldsm = 256; g.smB = (long)Cc * 256; g.smSlice = 0;
            mgemm<64, 0, 0, false, 0, false, false, false>
                <<<dim3(2, 4, Bc), blk, 0, stream>>>(g);
        }
        // o = (U @ WM^T)*0.5*dinv + g @ W2^T + BN partial stats
        //   + last-block BN finalize (scale/shift for next stage)
        {
            GP g{};
            g.A = U_sm; g.lda = 256; g.aB = NpC; g.aSl = 0;
            g.Bw = WMb; g.ldb = 256; g.bB = (long)Cc * 256; g.bSl = 0;
            g.K = 256; g.nsl = 1;
            g.A2 = g_sm; g.lda2 = 128; g.aB2 = (long)Np * 128;
            g.B2 = W2h + (size_t)s * Cc * Pc; g.ldb2 = 128; g.bB2 = 0;
            g.K2 = 128;
            g.outSM = o_sm; g.ldsm = 256; g.smB = NpC; g.smSlice = 0;
            g.ps = ps; g.ps2 = ps2;
            g.dinv = dinv;
            g.cnt = cnts + s;
            g.gammap = gamma + (size_t)s * Cc;
            g.betap = beta + (size_t)s * Cc;
            g.osc = scale; g.osh = shiftb;
            mgemm<128, 0, 0, false, 2, false, false, true>
                <<<dim3(2, 25, Bc), blk, 0, stream>>>(g);
        }
    }

    // final: d_out = transpose(out_sm + BN(o_sm))
    xpoutbn_k<<<dim3(49, 4, Bc), blk, 0, stream>>>(out_sm, o_sm, scale, shiftb,
                                                   (float*)d_out);
}

// Round 17
// 250.652 us; speedup vs baseline: 2.0285x; 1.4894x over previous
//
#include <hip/hip_runtime.h>

#define VMC(n) asm volatile("s_waitcnt vmcnt(" #n ")" ::: "memory")
#define LGKM0() asm volatile("s_waitcnt lgkmcnt(0)" ::: "memory")

namespace {

constexpr int Bc = 4;
constexpr int Cc = 256;
constexpr int Pc = 128;
constexpr int NcT = 3136;  // true spatial size 56*56
constexpr int Np = 3200;   // padded to 25*128
constexpr int Sc = 5;
constexpr int KSn = 5;     // split-K chunks for abt (3200 = 5*640)
constexpr int KCH = 640;
constexpr float EPSc = 1e-5f;

typedef __attribute__((ext_vector_type(8))) short bf16x8;
typedef __attribute__((ext_vector_type(4))) float f32x4;
typedef __attribute__((ext_vector_type(8))) unsigned short u16x8;
typedef __attribute__((ext_vector_type(4))) unsigned short u16x4;

__device__ inline float bf2f(unsigned short u) {
    return __uint_as_float(((unsigned)u) << 16);
}
__device__ inline unsigned short f2bf(float f) {
    unsigned u = __float_as_uint(f);
    return (unsigned short)((u + 0x7FFFu + ((u >> 16) & 1u)) >> 16);
}

struct GP {
    const unsigned short* A; int lda; long aB; long aSl;
    const unsigned short* Bw; int ldb; long bB; long bSl;
    const unsigned short* A2; int lda2; long aB2;
    const unsigned short* B2; int ldb2; long bB2;
    int K; int K2; int nsl; int kchunk;
    unsigned short* outSM; int ldsm; long smB; long smSlice;
    unsigned short* outCM; long cmB;
    float* ps; float* ps2;
    const float* bnsc; const float* bnsh;   // FUSEBN precomputed scale/shift
    const float* dinv;
    const unsigned short* oin;
    float* resid;
};

// ---------------------------------------------------------------------------
// MFMA GEMM: D[m][n] = sum over slices/loops of A[m][k]*B[n][k] (K-contig).
// Tile MT(m) x 128(n), 4 waves, K-step 64. Non-FUSEBN path: 4-buffer depth-3
// pipeline with counted vmcnt + raw s_barrier. FUSEBN path: explicit 4-step
// (K=256) depth-2 register-prefetch (fbIssue/fbFin split) pipeline.
// Staging via global_load_lds(16B), granule swizzle phys = g ^ (row&7).
// EPI: 0 none, 1 relu.  CMOUT: 0 none, 1 plain col-major, 2 col-major*dinv[m]
// SPLITK: z=ks*4+b, K range [ks*kchunk,+kchunk), out += ks*smSlice
// BNSTAT: 1 col sums->ps, 2 +sumsq->ps2.  FUSEBN: A = resid + BN(oin), resid
// updated.  XORM: row-major store to row (m0^128)+r.  DUALK: 2nd loop (A2,B2);
// accumulators scaled by 0.5*dinv[m] between loop1 and loop2.
// ---------------------------------------------------------------------------
template <int MT, int EPI, int CMOUT, bool SPLITK, int BNSTAT, bool FUSEBN,
          bool XORM, bool DUALK>
__global__ __launch_bounds__(256) void mgemm(GP p)
{
    constexpr int TBA = MT * 64 * 2;
    constexpr int TBB = 128 * 64 * 2;
    constexpr int BUF = TBA + TBB;
    constexpr int OTB = MT * 132 * 4;
    constexpr int LDSZ = (4 * BUF > OTB + 2048) ? 4 * BUF : (OTB + 2048);
    __shared__ __align__(16) char lds[LDSZ];

    int b, kstart;
    long smOff;
    if (SPLITK) {
        b = blockIdx.z & 3;
        int ks = blockIdx.z >> 2;
        kstart = ks * p.kchunk;
        smOff = (long)ks * p.smSlice;
    } else {
        b = blockIdx.z; kstart = 0; smOff = 0;
    }
    const int n0 = blockIdx.x * 128;
    const int m0 = blockIdx.y * MT;
    const int tid = threadIdx.x;
    const int w = tid >> 6, l = tid & 63;

    const unsigned short* Ab = p.A + (size_t)b * p.aB + (size_t)m0 * p.lda;
    const unsigned short* Bb = p.Bw + (size_t)b * p.bB + (size_t)n0 * p.ldb;

    const int srow8 = tid >> 3;                  // 0..31
    const int sgran = tid & 7;
    const int sswz = (sgran ^ (srow8 & 7)) * 8;  // swizzled source granule
    constexpr int AR = MT / 32;                  // A staging rounds

    constexpr int WC = (MT == 128) ? 2 : 4;      // waves along n
    constexpr int NB = 128 / WC / 16;            // B frags per wave
    const int wr = w / WC, wc = w % WC;

    f32x4 acc[4][NB] = {};

    // DUALK: preload 0.5*dinv for this lane's accumulator rows
    float4 dvv[4];
    if constexpr (DUALK) {
#pragma unroll
        for (int r = 0; r < 4; ++r) {
            float4 v = *(const float4*)(p.dinv + (size_t)b * Np + m0 +
                                        wr * 64 + r * 16 + (l >> 4) * 4);
            v.x *= 0.5f; v.y *= 0.5f; v.z *= 0.5f; v.w *= 0.5f;
            dvv[r] = v;
        }
    }

    auto stage1 = [&](int buf, int sl, int k0) {
        char* base = lds + buf * BUF;
        const unsigned short* As = Ab + (size_t)sl * p.aSl + k0 + sswz;
#pragma unroll
        for (int j = 0; j < AR; ++j)
            __builtin_amdgcn_global_load_lds(
                (const __attribute__((address_space(1))) void*)
                    (As + (size_t)(j * 32 + srow8) * p.lda),
                (__attribute__((address_space(3))) void*)(base + j * 4096 + tid * 16),
                16, 0, 0);
        const unsigned short* Bs = Bb + (size_t)sl * p.bSl + k0 + sswz;
#pragma unroll
        for (int j = 0; j < 4; ++j)
            __builtin_amdgcn_global_load_lds(
                (const __attribute__((address_space(1))) void*)
                    (Bs + (size_t)(j * 32 + srow8) * p.ldb),
                (__attribute__((address_space(3))) void*)(base + TBA + j * 4096 + tid * 16),
                16, 0, 0);
    };

    auto stageB1 = [&](int buf, int k0) {
        char* base = lds + buf * BUF + TBA;
        const unsigned short* Bs = Bb + k0 + sswz;
#pragma unroll
        for (int j = 0; j < 4; ++j)
            __builtin_amdgcn_global_load_lds(
                (const __attribute__((address_space(1))) void*)
                    (Bs + (size_t)(j * 32 + srow8) * p.ldb),
                (__attribute__((address_space(3))) void*)(base + j * 4096 + tid * 16),
                16, 0, 0);
    };

    auto compute = [&](int buf) {
        const char* base = lds + buf * BUF;
        const int lo = l & 15, gq = l >> 4;
#pragma unroll
        for (int kh = 0; kh < 2; ++kh) {
            const int lg = kh * 4 + gq;
            bf16x8 bf[NB];
#pragma unroll
            for (int c = 0; c < NB; ++c) {
                int brow = wc * (16 * NB) + c * 16 + lo;
                bf[c] = *(const bf16x8*)(base + TBA + brow * 128 +
                                         ((lg ^ (brow & 7)) << 4));
            }
#pragma unroll
            for (int r = 0; r < 4; ++r) {
                int arow = wr * 64 + r * 16 + lo;
                bf16x8 af = *(const bf16x8*)(base + arow * 128 +
                                             ((lg ^ (arow & 7)) << 4));
#pragma unroll
                for (int c = 0; c < NB; ++c)
                    acc[r][c] = __builtin_amdgcn_mfma_f32_16x16x32_bf16(
                        af, bf[c], acc[r][c], 0, 0, 0);
            }
        }
    };

    if constexpr (FUSEBN) {
        // K == 256: explicit 4-step, depth-2 register prefetch, 4 buffers.
        struct FB {
            u16x8 ov[AR]; float4 r0[AR], r1[AR];
            float4 s0, s1, h0, h1; int k0;
        };
        FB fA, fB;
        auto fbIssue = [&](FB& f, int k0) {   // 10 vm loads
            f.k0 = k0;
            f.s0 = *(const float4*)(p.bnsc + k0 + sgran * 8);
            f.s1 = *(const float4*)(p.bnsc + k0 + sgran * 8 + 4);
            f.h0 = *(const float4*)(p.bnsh + k0 + sgran * 8);
            f.h1 = *(const float4*)(p.bnsh + k0 + sgran * 8 + 4);
#pragma unroll
            for (int j = 0; j < AR; ++j) {
                size_t off = ((size_t)b * Np + (m0 + j * 32 + srow8)) * 256 +
                             k0 + sgran * 8;
                f.ov[j] = *(const u16x8*)(p.oin + off);
                f.r0[j] = *(const float4*)(p.resid + off);
                f.r1[j] = *(const float4*)(p.resid + off + 4);
            }
        };
        auto fbFin = [&](FB& f, int buf) {    // 4 vm stores + AR ds_writes
            char* base = lds + buf * BUF;
#pragma unroll
            for (int j = 0; j < AR; ++j) {
                int row = j * 32 + srow8;
                int n = m0 + row;
                size_t off = ((size_t)b * Np + n) * 256 + f.k0 + sgran * 8;
                bool real = (n < NcT);
                float fu[8];
                fu[0] = real ? f.r0[j].x + fmaf(bf2f(f.ov[j][0]), f.s0.x, f.h0.x) : 0.f;
                fu[1] = real ? f.r0[j].y + fmaf(bf2f(f.ov[j][1]), f.s0.y, f.h0.y) : 0.f;
                fu[2] = real ? f.r0[j].z + fmaf(bf2f(f.ov[j][2]), f.s0.z, f.h0.z) : 0.f;
                fu[3] = real ? f.r0[j].w + fmaf(bf2f(f.ov[j][3]), f.s0.w, f.h0.w) : 0.f;
                fu[4] = real ? f.r1[j].x + fmaf(bf2f(f.ov[j][4]), f.s1.x, f.h1.x) : 0.f;
                fu[5] = real ? f.r1[j].y + fmaf(bf2f(f.ov[j][5]), f.s1.y, f.h1.y) : 0.f;
                fu[6] = real ? f.r1[j].z + fmaf(bf2f(f.ov[j][6]), f.s1.z, f.h1.z) : 0.f;
                fu[7] = real ? f.r1[j].w + fmaf(bf2f(f.ov[j][7]), f.s1.w, f.h1.w) : 0.f;
                float4 w0, w1;
                w0.x = fu[0]; w0.y = fu[1]; w0.z = fu[2]; w0.w = fu[3];
                w1.x = fu[4]; w1.y = fu[5]; w1.z = fu[6]; w1.w = fu[7];
                *(float4*)(p.resid + off) = w0;
                *(float4*)(p.resid + off + 4) = w1;
                u16x8 hv;
#pragma unroll
                for (int i = 0; i < 8; ++i) hv[i] = f2bf(fu[i]);
                *(u16x8*)(base + row * 128 + ((sgran ^ (row & 7)) << 4)) = hv;
            }
        };

        fbIssue(fA, kstart);        stageB1(0, kstart);
        fbIssue(fB, kstart + 64);   stageB1(1, kstart + 64);
        // it0: drain fbA(10)+sB0(4); keep fbB+sB1 in flight
        VMC(14);
        fbFin(fA, 0);
        fbIssue(fA, kstart + 128);  stageB1(2, kstart + 128);
        LGKM0();
        __builtin_amdgcn_s_barrier();
        __builtin_amdgcn_sched_barrier(0);
        compute(0);
        // it1: [fbB sB1][st0][fbA' sB2]=32 -> 18 keeps st0+fbA'+sB2
        VMC(18);
        fbFin(fB, 1);
        fbIssue(fB, kstart + 192);  stageB1(3, kstart + 192);
        LGKM0();
        __builtin_amdgcn_s_barrier();
        __builtin_amdgcn_sched_barrier(0);
        compute(1);
        // it2: [st0][fbA' sB2][st1][fbB' sB3]=36 -> 18 keeps st1+fbB'+sB3
        VMC(18);
        fbFin(fA, 2);
        LGKM0();
        __builtin_amdgcn_s_barrier();
        __builtin_amdgcn_sched_barrier(0);
        compute(2);
        // it3: [st1][fbB' sB3][st2]=22 -> 4 keeps st2
        VMC(4);
        fbFin(fB, 3);
        LGKM0();
        __builtin_amdgcn_s_barrier();
        __builtin_amdgcn_sched_barrier(0);
        compute(3);
        __syncthreads();
    } else {
        const int nsteps1 = (SPLITK ? p.kchunk : p.K) >> 6;
        const int spl2 = DUALK ? (p.K2 >> 6) : 0;
        const int loop1 = p.nsl * nsteps1;
        const int tot = loop1 + spl2;

        const unsigned short* Ab2 = DUALK ?
            (p.A2 + (size_t)b * p.aB2 + (size_t)m0 * p.lda2) : nullptr;
        const unsigned short* Bb2 = DUALK ?
            (p.B2 + (size_t)b * p.bB2 + (size_t)n0 * p.ldb2) : nullptr;
        auto stage2 = [&](int buf, int k0) {
            if constexpr (DUALK) {
                char* base = lds + buf * BUF;
                const unsigned short* As = Ab2 + k0 + sswz;
#pragma unroll
                for (int j = 0; j < AR; ++j)
                    __builtin_amdgcn_global_load_lds(
                        (const __attribute__((address_space(1))) void*)
                            (As + (size_t)(j * 32 + srow8) * p.lda2),
                        (__attribute__((address_space(3))) void*)(base + j * 4096 + tid * 16),
                        16, 0, 0);
                const unsigned short* Bs = Bb2 + k0 + sswz;
#pragma unroll
                for (int j = 0; j < 4; ++j)
                    __builtin_amdgcn_global_load_lds(
                        (const __attribute__((address_space(1))) void*)
                            (Bs + (size_t)(j * 32 + srow8) * p.ldb2),
                        (__attribute__((address_space(3))) void*)(base + TBA + j * 4096 + tid * 16),
                        16, 0, 0);
            }
        };

        auto stage_g = [&](int buf, int g) {
            if (g < loop1) {
                int sl = g / nsteps1;
                int st = g - sl * nsteps1;
                stage1(buf, sl, kstart + (st << 6));
            } else {
                stage2(buf, (g - loop1) << 6);
            }
        };

        stage_g(0, 0);
        if (1 < tot) stage_g(1, 1);
        if (2 < tot) stage_g(2, 2);
        for (int gs = 0; gs < tot; ++gs) {
            if constexpr (MT == 64) {
                if (gs + 2 < tot) VMC(12);
                else if (gs + 1 < tot) VMC(6);
                else VMC(0);
            } else {
                if (gs + 2 < tot) VMC(16);
                else if (gs + 1 < tot) VMC(8);
                else VMC(0);
            }
            __builtin_amdgcn_s_barrier();
            __builtin_amdgcn_sched_barrier(0);
            if (gs + 3 < tot) stage_g((gs + 3) & 3, gs + 3);
            compute(gs & 3);
            if constexpr (DUALK) {
                if (gs == loop1 - 1) {   // scale loop1 accumulation by 0.5*dinv[m]
#pragma unroll
                    for (int r = 0; r < 4; ++r) {
#pragma unroll
                        for (int c = 0; c < NB; ++c) {
                            acc[r][c][0] *= dvv[r].x;
                            acc[r][c][1] *= dvv[r].y;
                            acc[r][c][2] *= dvv[r].z;
                            acc[r][c][3] *= dvv[r].w;
                        }
                    }
                }
            }
        }
        __syncthreads();
    }

    // stage accumulators to LDS f32 [MT][132]
    float* ot = (float*)lds;
    {
        const int lo = l & 15, gq = l >> 4;
#pragma unroll
        for (int r = 0; r < 4; ++r)
#pragma unroll
            for (int c = 0; c < NB; ++c)
#pragma unroll
                for (int j = 0; j < 4; ++j) {
                    float v = acc[r][c][j];
                    if (EPI == 1) v = fmaxf(v, 0.f);
                    ot[(wr * 64 + r * 16 + gq * 4 + j) * 132 +
                       wc * (16 * NB) + c * 16 + lo] = v;
                }
    }
    __syncthreads();

    {   // row-major store
        constexpr int TPR = 256 / MT;
        const int r = tid / TPR;
        const int c0 = (tid % TPR) * (MT / 2);
        const int m0s = XORM ? (m0 ^ 128) : m0;
        unsigned short* dst = p.outSM + (size_t)b * p.smB + smOff +
                              (size_t)(m0s + r) * p.ldsm + n0 + c0;
#pragma unroll
        for (int k = 0; k < MT / 16; ++k) {
            u16x8 o;
#pragma unroll
            for (int j = 0; j < 8; ++j) o[j] = f2bf(ot[r * 132 + c0 + 8 * k + j]);
            *(u16x8*)(dst + 8 * k) = o;
        }
    }

    if (CMOUT) {   // column-major store
        const int c = tid >> 1, r0 = (tid & 1) * (MT / 2);
        const float* dv = p.dinv + (size_t)b * Np + m0 + r0;
        unsigned short* dst = p.outCM + (size_t)b * p.cmB +
                              (size_t)(n0 + c) * Np + m0 + r0;
#pragma unroll
        for (int k = 0; k < MT / 16; ++k) {
            u16x8 o;
#pragma unroll
            for (int j = 0; j < 8; ++j) {
                float v = ot[(r0 + 8 * k + j) * 132 + c];
                if (CMOUT == 2) v *= dv[8 * k + j];
                o[j] = f2bf(v);
            }
            *(u16x8*)(dst + 8 * k) = o;
        }
    }

    if (BNSTAT) {
        float* p1 = (float*)(lds + OTB);
        float* p2 = p1 + 256;
        const int col = tid & 127, half = tid >> 7;
        float s = 0.f, s2 = 0.f;
#pragma unroll
        for (int i = 0; i < MT / 2; ++i) {
            float v = ot[(half * (MT / 2) + i) * 132 + col];
            s += v;
            if (BNSTAT == 2) s2 = fmaf(v, v, s2);
        }
        p1[half * 128 + col] = s;
        if (BNSTAT == 2) p2[half * 128 + col] = s2;
        __syncthreads();
        if (tid < 128) {
            float aa = p1[tid] + p1[128 + tid];
            size_t slot = ((size_t)b * gridDim.y + blockIdx.y) * 256 + n0 + tid;
            p.ps[slot] = aa;
            if (BNSTAT == 2) p.ps2[slot] = p2[tid] + p2[128 + tid];
        }
    }
}

// ---------------------------------------------------------------------------
// prep: weight f32->bf16 (544 items) + input transpose (800 items)
// ---------------------------------------------------------------------------
__global__ __launch_bounds__(256) void prep_k(
    const float* __restrict__ x, const float* __restrict__ Wt,
    const float* __restrict__ Wp, const float* __restrict__ Wg,
    const float* __restrict__ W1, const float* __restrict__ W2,
    unsigned short* __restrict__ Wcomb, unsigned short* __restrict__ Wgh,
    unsigned short* __restrict__ W1h, unsigned short* __restrict__ W2h,
    float* __restrict__ out_sm, unsigned short* __restrict__ outh)
{
    __shared__ float tb[64][65];
    int item = blockIdx.x;
    int t = threadIdx.x;
    if (item < 544) {
        size_t e = ((size_t)item * 256 + t) * 4;
        const float* src; unsigned short* dst;
        if (e < 32768)       { src = Wt + e;           dst = Wcomb + e; }
        else if (e < 65536)  { src = Wp + (e - 32768); dst = Wcomb + e; }
        else if (e < 229376) { size_t o = e - 65536;  src = Wg + o; dst = Wgh + o; }
        else if (e < 393216) { size_t o = e - 229376; src = W1 + o; dst = W1h + o; }
        else                 { size_t o = e - 393216; src = W2 + o; dst = W2h + o; }
        float4 v = *(const float4*)src;
        u16x4 t4;
        t4[0] = f2bf(v.x); t4[1] = f2bf(v.y); t4[2] = f2bf(v.z); t4[3] = f2bf(v.w);
        *(u16x4*)dst = t4;
        return;
    }
    int it = item - 544;
    int nx = it % 50, cy = (it / 50) % 4, b = it / 200;
    int c0 = cy * 64, n0 = nx * 64;
    const bool pad = (n0 >= NcT);
    if (!pad) {
        int ci = t >> 2, nb = (t & 3) * 16;
        const float* src = x + ((size_t)b * Cc + c0 + ci) * NcT + n0 + nb;
#pragma unroll
        for (int k = 0; k < 4; ++k) {
            float4 v = *(const float4*)(src + 4 * k);
            tb[ci][nb + 4 * k + 0] = v.x; tb[ci][nb + 4 * k + 1] = v.y;
            tb[ci][nb + 4 * k + 2] = v.z; tb[ci][nb + 4 * k + 3] = v.w;
        }
    }
    __syncthreads();
    int r = t >> 2, cb = (t & 3) * 16;
    size_t off = ((size_t)b * Np + n0 + r) * 256 + c0 + cb;
    float vv[16];
#pragma unroll
    for (int j = 0; j < 16; ++j) vv[j] = pad ? 0.f : tb[cb + j][r];
    float* dst = out_sm + off;
#pragma unroll
    for (int k = 0; k < 4; ++k) {
        float4 v; v.x = vv[4*k]; v.y = vv[4*k+1]; v.z = vv[4*k+2]; v.w = vv[4*k+3];
        *(float4*)(dst + 4 * k) = v;
    }
    u16x8 h1, h2;
#pragma unroll
    for (int j = 0; j < 8; ++j) { h1[j] = f2bf(vv[j]); h2[j] = f2bf(vv[8 + j]); }
    unsigned short* dh = outh + off;
    *(u16x8*)dh = h1;
    *(u16x8*)(dh + 8) = h2;
}

// dinv[b][i] = d>0 ? rsqrt(d) : 0, d = 0.5*sum_q U[b][i][q]*rs[b][q^128]
__global__ __launch_bounds__(256) void dinv_k(
    const unsigned short* __restrict__ U, const float* __restrict__ rp,
    float* __restrict__ dinv)
{
    __shared__ float rsl[256];
    int b = blockIdx.y, tid = threadIdx.x;
    float s = 0.f;
    for (int j = 0; j < 25; ++j) s += rp[((size_t)b * 25 + j) * 256 + tid];
    rsl[tid ^ 128] = s;
    __syncthreads();
    int i = blockIdx.x * 256 + tid;
    if (i < Np) {
        const unsigned short* row = U + ((size_t)b * Np + i) * 256;
        float acc = 0.f;
        for (int q0 = 0; q0 < 256; q0 += 8) {
            u16x8 v = *(const u16x8*)(row + q0);
#pragma unroll
            for (int j = 0; j < 8; ++j) acc = fmaf(bf2f(v[j]), rsl[q0 + j], acc);
        }
        float d = 0.5f * acc;
        dinv[(size_t)b * Np + i] = d > 0.f ? rsqrtf(d) : 0.f;
    }
}

// BN finalize: 16 blocks x 16 channels; 100 partial groups
__global__ __launch_bounds__(256) void bnfin_k(
    const float* __restrict__ ps, const float* __restrict__ ps2,
    const float* __restrict__ gamma, const float* __restrict__ beta,
    float* __restrict__ scale, float* __restrict__ shift)
{
    __shared__ float l1[256], l2[256];
    int t = threadIdx.x;
    int c = blockIdx.x * 16 + (t & 15);
    int gl = t >> 4;
    float a = 0.f, a2 = 0.f;
    for (int g = gl; g < 100; g += 16) {
        a += ps[(size_t)g * 256 + c];
        a2 += ps2[(size_t)g * 256 + c];
    }
    l1[t] = a; l2[t] = a2;
    __syncthreads();
    if (gl == 0) {
#pragma unroll
        for (int j = 1; j < 16; ++j) {
            a += l1[j * 16 + (t & 15)];
            a2 += l2[j * 16 + (t & 15)];
        }
        const float inv = 1.f / (float)(Bc * NcT);
        float mean = a * inv;
        float var = a2 * inv - mean * mean;
        float sc = gamma[c] * rsqrtf(var + EPSc);
        scale[c] = sc;
        shift[c] = beta[c] - mean * sc;
    }
}

// d_out[b][c][n] = transpose(out_sm + BN(o_sm))   (final stage fused)
__global__ __launch_bounds__(256) void xpoutbn_k(
    const float* __restrict__ out_sm, const unsigned short* __restrict__ oin,
    const float* __restrict__ scale, const float* __restrict__ shift,
    float* __restrict__ outp)
{
    __shared__ float tb[64][65];
    __shared__ float lsc[64], lsh[64];
    int b = blockIdx.z, c0 = blockIdx.y * 64, n0 = blockIdx.x * 64;
    int t = threadIdx.x;
    if (t < 64) { lsc[t] = scale[c0 + t]; lsh[t] = shift[c0 + t]; }
    __syncthreads();
    {
        int r = t >> 2, cb = (t & 3) * 16;
        size_t off = ((size_t)b * Np + n0 + r) * 256 + c0 + cb;
#pragma unroll
        for (int k = 0; k < 2; ++k) {
            float4 a0 = *(const float4*)(out_sm + off + 8 * k);
            float4 a1 = *(const float4*)(out_sm + off + 8 * k + 4);
            u16x8 ov = *(const u16x8*)(oin + off + 8 * k);
            tb[r][cb + 8*k + 0] = a0.x + fmaf(bf2f(ov[0]), lsc[cb + 8*k + 0], lsh[cb + 8*k + 0]);
            tb[r][cb + 8*k + 1] = a0.y + fmaf(bf2f(ov[1]), lsc[cb + 8*k + 1], lsh[cb + 8*k + 1]);
            tb[r][cb + 8*k + 2] = a0.z + fmaf(bf2f(ov[2]), lsc[cb + 8*k + 2], lsh[cb + 8*k + 2]);
            tb[r][cb + 8*k + 3] = a0.w + fmaf(bf2f(ov[3]), lsc[cb + 8*k + 3], lsh[cb + 8*k + 3]);
            tb[r][cb + 8*k + 4] = a1.x + fmaf(bf2f(ov[4]), lsc[cb + 8*k + 4], lsh[cb + 8*k + 4]);
            tb[r][cb + 8*k + 5] = a1.y + fmaf(bf2f(ov[5]), lsc[cb + 8*k + 5], lsh[cb + 8*k + 5]);
            tb[r][cb + 8*k + 6] = a1.z + fmaf(bf2f(ov[6]), lsc[cb + 8*k + 6], lsh[cb + 8*k + 6]);
            tb[r][cb + 8*k + 7] = a1.w + fmaf(bf2f(ov[7]), lsc[cb + 8*k + 7], lsh[cb + 8*k + 7]);
        }
    }
    __syncthreads();
    {
        int c = t >> 2, rb = (t & 3) * 16;
        float vv[16];
#pragma unroll
        for (int j = 0; j < 16; ++j) vv[j] = tb[rb + j][c];
        float* dst = outp + ((size_t)b * Cc + c0 + c) * NcT + n0 + rb;
#pragma unroll
        for (int k = 0; k < 4; ++k) {
            float4 v; v.x = vv[4*k]; v.y = vv[4*k+1]; v.z = vv[4*k+2]; v.w = vv[4*k+3];
            *(float4*)(dst + 4 * k) = v;
        }
    }
}

}  // namespace

extern "C" void kernel_launch(void* const* d_in, const int* in_sizes, int n_in,
                              void* d_out, int out_size, void* d_ws, size_t ws_size,
                              hipStream_t stream) {
    const float* x     = (const float*)d_in[0];
    const float* Wt    = (const float*)d_in[1];
    const float* Wp    = (const float*)d_in[2];
    const float* Wg    = (const float*)d_in[3];
    const float* W1    = (const float*)d_in[4];
    const float* W2    = (const float*)d_in[5];
    const float* gamma = (const float*)d_in[6];
    const float* beta  = (const float*)d_in[7];

    char* p = (char*)d_ws;
    auto alloc = [&](size_t bytes) { char* r = p; p += (bytes + 255) & ~(size_t)255; return r; };
    float*          out_sm = (float*)         alloc((size_t)Bc * Np * 256 * 4);
    unsigned short* outh   = (unsigned short*)alloc((size_t)Bc * Np * 256 * 2);
    unsigned short* U_sm   = (unsigned short*)alloc((size_t)Bc * Np * 256 * 2);
    unsigned short* U_cm   = (unsigned short*)alloc((size_t)Bc * 256 * Np * 2);
    unsigned short* g_sm   = (unsigned short*)alloc((size_t)Bc * Np * Pc * 2);
    unsigned short* g_cmd  = (unsigned short*)alloc((size_t)Bc * Pc * Np * 2);
    unsigned short* o_sm   = (unsigned short*)alloc((size_t)Bc * Np * 256 * 2);
    unsigned short* Cpart  = (unsigned short*)alloc((size_t)KSn * Bc * 256 * Pc * 2);
    unsigned short* WMb    = (unsigned short*)alloc((size_t)Bc * Cc * 256 * 2);
    unsigned short* Wcomb  = (unsigned short*)alloc((size_t)Cc * Cc * 2);
    unsigned short* Wgh    = (unsigned short*)alloc((size_t)Sc * Pc * Cc * 2);
    unsigned short* W1h    = (unsigned short*)alloc((size_t)Sc * Cc * Pc * 2);
    unsigned short* W2h    = (unsigned short*)alloc((size_t)Sc * Cc * Pc * 2);
    float*          rp     = (float*)         alloc((size_t)100 * 256 * 4);
    float*          dinv   = (float*)         alloc((size_t)Bc * Np * 4);
    float*          ps     = (float*)         alloc((size_t)100 * 256 * 4);
    float*          ps2    = (float*)         alloc((size_t)100 * 256 * 4);
    float*          scale  = (float*)         alloc(256 * 4);
    float*          shiftb = (float*)         alloc(256 * 4);

    const long NpC = (long)Np * 256;
    dim3 blk(256);

    prep_k<<<1344, blk, 0, stream>>>(x, Wt, Wp, Wg, W1, W2,
                                     Wcomb, Wgh, W1h, W2h, out_sm, outh);

    // U = relu([Wt;Wp] @ x): spatial-major + col-major + col sums
    {
        GP g{};
        g.A = outh; g.lda = 256; g.aB = NpC; g.aSl = 0;
        g.Bw = Wcomb; g.ldb = 256; g.bB = 0; g.bSl = 0;
        g.K = 256; g.nsl = 1;
        g.outSM = U_sm; g.ldsm = 256; g.smB = NpC; g.smSlice = 0;
        g.outCM = U_cm; g.cmB = (long)256 * Np;
        g.ps = rp;
        mgemm<128, 1, 1, false, 1, false, false, false>
            <<<dim3(2, 25, Bc), blk, 0, stream>>>(g);
    }

    dinv_k<<<dim3(13, Bc), blk, 0, stream>>>(U_sm, rp, dinv);

    for (int s = 0; s < Sc; ++s) {
        // g = Wg[s] @ out  (FUSEBN applies previous stage's BN to residual)
        {
            GP g{};
            g.A = outh; g.lda = 256; g.aB = NpC; g.aSl = 0;
            g.Bw = Wgh + (size_t)s * Pc * Cc; g.ldb = 256; g.bB = 0; g.bSl = 0;
            g.K = 256; g.nsl = 1;
            g.outSM = g_sm; g.ldsm = 128; g.smB = (long)Np * 128; g.smSlice = 0;
            g.outCM = g_cmd; g.cmB = (long)Pc * Np;
            g.dinv = dinv;
            g.oin = o_sm; g.bnsc = scale; g.bnsh = shiftb; g.resid = out_sm;
            if (s == 0)
                mgemm<64, 0, 2, false, 0, false, false, false>
                    <<<dim3(1, 50, Bc), blk, 0, stream>>>(g);
            else
                mgemm<64, 0, 2, false, 0, true, false, false>
                    <<<dim3(1, 50, Bc), blk, 0, stream>>>(g);
        }
        // Cpart[ks][b][q^128][p] = partial_i U_cm[q][i] * g_cmd[p][i]
        {
            GP g{};
            g.A = U_cm; g.lda = Np; g.aB = (long)256 * Np; g.aSl = 0;
            g.Bw = g_cmd; g.ldb = Np; g.bB = (long)Pc * Np; g.bSl = 0;
            g.K = Np; g.kchunk = KCH; g.nsl = 1;
            g.outSM = Cpart; g.ldsm = 128; g.smB = (long)256 * Pc;
            g.smSlice = (long)Bc * 256 * Pc;
            mgemm<64, 0, 0, true, 0, false, true, false>
                <<<dim3(1, 4, KSn * Bc), blk, 0, stream>>>(g);
        }
        // WM[b][c][q] = sum_ks sum_p W1[c][p] * Cpart[ks][b][q][p]
        {
            GP g{};
            g.A = W1h + (size_t)s * Cc * Pc; g.lda = 128; g.aB = 0; g.aSl = 0;
            g.Bw = Cpart; g.ldb = 128; g.bB = (long)256 * Pc;
            g.bSl = (long)Bc * 256 * Pc;
            g.K = 128; g.nsl = KSn;
            g.outSM = WMb; g.ldsm = 256; g.smB = (long)Cc * 256; g.smSlice = 0;
            mgemm<64, 0, 0, false, 0, false, false, false>
                <<<dim3(2, 4, Bc), blk, 0, stream>>>(g);
        }
        // o = (U @ WM^T) * 0.5*dinv[m] + g @ W2^T  + BN partial stats
        {
            GP g{};
            g.A = U_sm; g.lda = 256; g.aB = NpC; g.aSl = 0;
            g.Bw = WMb; g.ldb = 256; g.bB = (long)Cc * 256; g.bSl = 0;
            g.K = 256; g.nsl = 1;
            g.A2 = g_sm; g.lda2 = 128; g.aB2 = (long)Np * 128;
            g.B2 = W2h + (size_t)s * Cc * Pc; g.ldb2 = 128; g.bB2 = 0;
            g.K2 = 128;
            g.outSM = o_sm; g.ldsm = 256; g.smB = NpC; g.smSlice = 0;
            g.ps = ps; g.ps2 = ps2;
            g.dinv = dinv;
            mgemm<128, 0, 0, false, 2, false, false, true>
                <<<dim3(2, 25, Bc), blk, 0, stream>>>(g);
        }
        bnfin_k<<<16, blk, 0, stream>>>(ps, ps2, gamma + s * Cc, beta + s * Cc,
                                        scale, shiftb);
    }

    // final: d_out = transpose(out_sm + BN(o_sm))
    xpoutbn_k<<<dim3(49, 4, Bc), blk, 0, stream>>>(out_sm, o_sm, scale, shiftb,
                                                   (float*)d_out);
}